// Round 14
// baseline (155.735 us; speedup 1.0000x reference)
//
#include <hip/hip_runtime.h>

#define EPS 1e-5f
constexpr int NN = 4096;
constexpr float INV_CNT = 1.0f / (8.0f * 4096.0f);
constexpr float LOG2E = 1.44269504f;

typedef __attribute__((ext_vector_type(8))) short bf16x8;
typedef __attribute__((ext_vector_type(4))) float f32x4;
typedef __attribute__((ext_vector_type(16))) float f32x16;
typedef __attribute__((ext_vector_type(4))) _Float16 f16x4;
typedef __fp16 fp16x2 __attribute__((ext_vector_type(2)));

#if __has_builtin(__builtin_amdgcn_exp2f)
#define EXP2F(x) __builtin_amdgcn_exp2f(x)
#else
#define EXP2F(x) exp2f(x)
#endif

// workspace layout (float offsets)
constexpr size_t OFF_QPT = 0;        // 524288  q pre-act, point-major [p][16]
constexpr size_t OFF_KPT = 524288;   // 524288
constexpr size_t OFF_VPT = 1048576;  // 131072  v pre-act, [p][4]
constexpr size_t OFF_WT2 = 1179648;  // 2304
constexpr size_t OFF_XP  = 1181952;  // 1152
constexpr size_t OFF_BS  = 1183104;  // 70*256 = 17920
constexpr size_t OFF_QH  = 1201024;  // 262144 (bf16 hi, [p][16] = 2 uint4/p)
constexpr size_t OFF_QL  = 1463168;  // 262144
constexpr size_t OFF_KH  = 1725312;  // 262144
constexpr size_t OFF_KL  = 1987456;  // 262144
constexpr size_t OFF_VFH = 2249600;  // 262144 fl = 16 rows x 32768 fp16 (rows 0-3 live)
constexpr size_t OFF_PL  = 2511744;  // 4*32768
constexpr size_t OFF_PA0 = 2642816;
constexpr size_t OFF_PA1 = 2773888;
constexpr size_t OFF_PA2 = 2904960;
constexpr size_t OFF_PMX = 3036032;  // 32768 per-row max; end 3068800 = 12.3 MB

// ---- kA: blocks 0-127: x moments; block 128: combined weights --------------
__global__ __launch_bounds__(256) void kA_mom_wcomb(
    const float* __restrict__ x, float* __restrict__ xpart,
    const float* __restrict__ w2, const float* __restrict__ wq,
    const float* __restrict__ wk, const float* __restrict__ wv,
    float* __restrict__ wt2) {
  __shared__ float w2s[8192];
  __shared__ float wr[4480];
  __shared__ float sred[36];
  int tx = threadIdx.x;
  if (blockIdx.x < 128) {
    int idx = blockIdx.x * 256 + tx;
    int b = idx >> 12, n = idx & 4095;
    float x0 = x[(size_t)(b*3+0)*NN + n];
    float x1 = x[(size_t)(b*3+1)*NN + n];
    float x2 = x[(size_t)(b*3+2)*NN + n];
    float m[9] = {x0, x1, x2, x0*x0, x0*x1, x0*x2, x1*x1, x1*x2, x2*x2};
    #pragma unroll
    for (int off = 32; off; off >>= 1) {
      #pragma unroll
      for (int j = 0; j < 9; ++j) m[j] += __shfl_xor(m[j], off);
    }
    int w = tx >> 6;
    if ((tx & 63) == 0) {
      #pragma unroll
      for (int j = 0; j < 9; ++j) sred[w*9+j] = m[j];
    }
    __syncthreads();
    if (tx < 9) xpart[tx*128 + blockIdx.x] = sred[tx] + sred[9+tx] + sred[18+tx] + sred[27+tx];
  } else {
    for (int i = tx; i < 8192; i += 256) w2s[i] = w2[i];
    for (int i = tx; i < 2048; i += 256) { wr[i] = wq[i]; wr[2048+i] = wk[i]; }
    for (int i = tx; i < 384; i += 256) wr[4096+i] = wv[i];
    __syncthreads();
    for (int e = tx; e < 2240; e += 256) {
      int j = e >> 6, c = e & 63;
      float s = 0.f;
      #pragma unroll 4
      for (int o = 0; o < 128; ++o) s = fmaf(wr[j*128+o], w2s[o*64+c], s);
      wt2[c*36 + j] = s;
    }
  }
}

// ---- kB: (f1 fused) per point -> qa/ka/va + block-partial stats ------------
__global__ __launch_bounds__(128) void kB_qkv(
    const float* __restrict__ x, const float* __restrict__ xpart,
    const float* __restrict__ w1, const float* __restrict__ g1,
    const float* __restrict__ b1, const float* __restrict__ wt2,
    float* __restrict__ qpT, float* __restrict__ kpT, float* __restrict__ vpT,
    float* __restrict__ bs) {
  __shared__ float4 w1s[64];
  __shared__ float4 wt2s[576];
  __shared__ float sred[140];
  __shared__ float mom[9];
  int tx = threadIdx.x;
  for (int i = tx; i < 576; i += 128) wt2s[i] = ((const float4*)wt2)[i];
  if (tx < 9) {
    float acc = 0.f;
    #pragma unroll 8
    for (int i = 0; i < 128; ++i) acc += xpart[tx*128 + i];
    mom[tx] = acc * INV_CNT;
  }
  __syncthreads();
  if (tx < 64) {
    int c = tx;
    float a = w1[c*3], b_ = w1[c*3+1], d = w1[c*3+2];
    float mean = a*mom[0] + b_*mom[1] + d*mom[2];
    float e2 = a*a*mom[3] + b_*b_*mom[6] + d*d*mom[8]
             + 2.f*(a*b_*mom[4] + a*d*mom[5] + b_*d*mom[7]);
    float sc = g1[c] * rsqrtf(e2 - mean*mean + EPS);
    w1s[c] = make_float4(a*sc, b_*sc, d*sc, fmaf(-mean, sc, b1[c]));
  }
  __syncthreads();
  int idx = blockIdx.x*128 + tx;
  int b = idx >> 12, n = idx & 4095;
  float x0 = x[(size_t)(b*3+0)*NN + n];
  float x1 = x[(size_t)(b*3+1)*NN + n];
  float x2 = x[(size_t)(b*3+2)*NN + n];
  float qa[16] = {}, ka[16] = {};
  float va0 = 0.f, va1 = 0.f, va2 = 0.f;
  #pragma unroll 4
  for (int c = 0; c < 64; ++c) {
    float4 w = w1s[c];
    float h = fmaf(w.x, x0, fmaf(w.y, x1, fmaf(w.z, x2, w.w)));
    h = h > 0.f ? h : 0.2f*h;
    #pragma unroll
    for (int j = 0; j < 4; ++j) {
      float4 A = wt2s[c*9 + j];
      qa[4*j+0] = fmaf(A.x, h, qa[4*j+0]);
      qa[4*j+1] = fmaf(A.y, h, qa[4*j+1]);
      qa[4*j+2] = fmaf(A.z, h, qa[4*j+2]);
      qa[4*j+3] = fmaf(A.w, h, qa[4*j+3]);
      float4 B = wt2s[c*9 + 4 + j];
      ka[4*j+0] = fmaf(B.x, h, ka[4*j+0]);
      ka[4*j+1] = fmaf(B.y, h, ka[4*j+1]);
      ka[4*j+2] = fmaf(B.z, h, ka[4*j+2]);
      ka[4*j+3] = fmaf(B.w, h, ka[4*j+3]);
    }
    float4 V = wt2s[c*9 + 8];
    va0 = fmaf(V.x, h, va0); va1 = fmaf(V.y, h, va1); va2 = fmaf(V.z, h, va2);
  }
  float4* qo = (float4*)(qpT + (size_t)idx*16);
  float4* ko = (float4*)(kpT + (size_t)idx*16);
  #pragma unroll
  for (int j = 0; j < 4; ++j) {
    qo[j] = make_float4(qa[4*j], qa[4*j+1], qa[4*j+2], qa[4*j+3]);
    ko[j] = make_float4(ka[4*j], ka[4*j+1], ka[4*j+2], ka[4*j+3]);
  }
  ((float4*)vpT)[idx] = make_float4(va0, va1, va2, 0.f);
  int w = tx >> 6;
  bool lead = ((tx & 63) == 0);
  #pragma unroll
  for (int d = 0; d < 16; ++d) {
    float s = qa[d], q = qa[d]*qa[d];
    #pragma unroll
    for (int off = 32; off; off >>= 1) { s += __shfl_xor(s, off); q += __shfl_xor(q, off); }
    if (lead) { sred[w*70 + d] = s; sred[w*70 + 16 + d] = q; }
    s = ka[d]; q = ka[d]*ka[d];
    #pragma unroll
    for (int off = 32; off; off >>= 1) { s += __shfl_xor(s, off); q += __shfl_xor(q, off); }
    if (lead) { sred[w*70 + 32 + d] = s; sred[w*70 + 48 + d] = q; }
  }
  float vv[3] = {va0, va1, va2};
  #pragma unroll
  for (int d = 0; d < 3; ++d) {
    float s = vv[d], q = vv[d]*vv[d];
    #pragma unroll
    for (int off = 32; off; off >>= 1) { s += __shfl_xor(s, off); q += __shfl_xor(q, off); }
    if (lead) { sred[w*70 + 64 + d] = s; sred[w*70 + 67 + d] = q; }
  }
  __syncthreads();
  if (tx < 70)
    bs[tx*256 + blockIdx.x] = sred[tx] + sred[70+tx];
}

// ---- kC: (f2 fused) BN+ReLU, q scaled by log2e, hi/lo split, v->fp16 -------
__global__ __launch_bounds__(256) void kC_prep(
    const float* __restrict__ qpT, const float* __restrict__ kpT,
    const float* __restrict__ vpT, const float* __restrict__ bs,
    const float* __restrict__ g2, const float* __restrict__ b2,
    const float* __restrict__ g3, const float* __restrict__ b3,
    const float* __restrict__ g4, const float* __restrict__ b4,
    uint4* __restrict__ qh, uint4* __restrict__ ql,
    uint4* __restrict__ kh, uint4* __restrict__ kl,
    _Float16* __restrict__ vfh) {
  __shared__ float tot[70];
  __shared__ float spr[70];
  int tx = threadIdx.x;
  if (tx < 70) {
    float acc = 0.f;
    #pragma unroll 8
    for (int i = 0; i < 256; ++i) acc += bs[tx*256 + i];
    tot[tx] = acc * INV_CNT;
  }
  __syncthreads();
  if (tx < 16) {
    float mean = tot[tx], var = tot[16+tx] - mean*mean;
    float sc = g2[tx]*rsqrtf(var + EPS);
    spr[tx] = sc * LOG2E;                                // q in log2 domain
    spr[16+tx] = fmaf(-mean, sc, b2[tx]) * LOG2E;
  } else if (tx < 32) {
    int d = tx-16;
    float mean = tot[32+d], var = tot[48+d] - mean*mean;
    float sc = g3[d]*rsqrtf(var + EPS);
    spr[32+d] = sc; spr[48+d] = fmaf(-mean, sc, b3[d]);
  } else if (tx < 35) {
    int d = tx-32;
    float mean = tot[64+d], var = tot[67+d] - mean*mean;
    float sc = g4[d]*rsqrtf(var + EPS);
    spr[64+d] = sc; spr[67+d] = fmaf(-mean, sc, b4[d]);
  }
  __syncthreads();
  int p = blockIdx.x*256 + tx;
  float qv[16], kv[16];
  const float4* q4 = (const float4*)(qpT + (size_t)p*16);
  const float4* k4p = (const float4*)(kpT + (size_t)p*16);
  #pragma unroll
  for (int j = 0; j < 4; ++j) {
    float4 tq = q4[j], tk = k4p[j];
    qv[4*j] = tq.x; qv[4*j+1] = tq.y; qv[4*j+2] = tq.z; qv[4*j+3] = tq.w;
    kv[4*j] = tk.x; kv[4*j+1] = tk.y; kv[4*j+2] = tk.z; kv[4*j+3] = tk.w;
  }
  #pragma unroll
  for (int d = 0; d < 16; ++d) {
    qv[d] = fmaxf(fmaf(qv[d], spr[d],    spr[16+d]), 0.f);
    kv[d] = fmaxf(fmaf(kv[d], spr[32+d], spr[48+d]), 0.f);
  }
  unsigned qhw[8], qlw[8], khw[8], klw[8];
  #pragma unroll
  for (int j = 0; j < 8; ++j) {
    unsigned u0 = __float_as_uint(qv[2*j]),   u1 = __float_as_uint(qv[2*j+1]);
    unsigned h0 = u0 & 0xFFFF0000u, h1 = u1 & 0xFFFF0000u;
    float l0 = qv[2*j] - __uint_as_float(h0);
    float l1 = qv[2*j+1] - __uint_as_float(h1);
    qhw[j] = (h0 >> 16) | h1;
    qlw[j] = (__float_as_uint(l0) >> 16) | (__float_as_uint(l1) & 0xFFFF0000u);
    u0 = __float_as_uint(kv[2*j]); u1 = __float_as_uint(kv[2*j+1]);
    h0 = u0 & 0xFFFF0000u; h1 = u1 & 0xFFFF0000u;
    l0 = kv[2*j] - __uint_as_float(h0);
    l1 = kv[2*j+1] - __uint_as_float(h1);
    khw[j] = (h0 >> 16) | h1;
    klw[j] = (__float_as_uint(l0) >> 16) | (__float_as_uint(l1) & 0xFFFF0000u);
  }
  qh[(size_t)p*2+0] = make_uint4(qhw[0], qhw[1], qhw[2], qhw[3]);
  qh[(size_t)p*2+1] = make_uint4(qhw[4], qhw[5], qhw[6], qhw[7]);
  ql[(size_t)p*2+0] = make_uint4(qlw[0], qlw[1], qlw[2], qlw[3]);
  ql[(size_t)p*2+1] = make_uint4(qlw[4], qlw[5], qlw[6], qlw[7]);
  kh[(size_t)p*2+0] = make_uint4(khw[0], khw[1], khw[2], khw[3]);
  kh[(size_t)p*2+1] = make_uint4(khw[4], khw[5], khw[6], khw[7]);
  kl[(size_t)p*2+0] = make_uint4(klw[0], klw[1], klw[2], klw[3]);
  kl[(size_t)p*2+1] = make_uint4(klw[4], klw[5], klw[6], klw[7]);
  float4 vv = ((const float4*)vpT)[p];
  vfh[0*32768 + p] = (_Float16)fmaxf(fmaf(vv.x, spr[64], spr[67]), 0.f);
  vfh[1*32768 + p] = (_Float16)fmaxf(fmaf(vv.y, spr[65], spr[68]), 0.f);
  vfh[2*32768 + p] = (_Float16)fmaxf(fmaf(vv.z, spr[66], spr[69]), 0.f);
  vfh[3*32768 + p] = (_Float16)1.0f;   // ones row -> l accumulates in PV MFMA
}

// ---- k5max: pass 1 — per-row max from HI-only scores, 32x32x16 tiles -------
// Truncation split => kl,ql >= 0 => c_hi <= c_full <= c_hi + ~0.78 (log2),
// so pass2's pw = 2^(c_full - Mhi) in (0, 1.72] — fp16-safe, softmax-exact.
// C layout (m74/m101): col = lane&31 (q point m), row = (reg&3)+8*(reg>>2)
// +4*(lane>>5) (k point n). A = kh rows (once), B = qh cols (swept).
__global__ __launch_bounds__(256, 4) void k5max(
    const uint4* __restrict__ qh, const uint4* __restrict__ kh,
    float* __restrict__ pmax) {
  int tx = threadIdx.x;
  int b  = blockIdx.x >> 5;      // 8 batches x 32 row-chunks (128 rows each)
  int rc = blockIdx.x & 31;
  int w = tx >> 6, lane = tx & 63;
  int cl = lane & 31, hl = lane >> 5;
  int n0 = rc*128 + w*32;
  size_t pbase = (size_t)b*4096;
  bf16x8 aK = *(const bf16x8*)&kh[(pbase + n0 + cl)*2 + hl];
  f32x16 zero16;
  #pragma unroll
  for (int r = 0; r < 16; ++r) zero16[r] = 0.f;
  f32x16 lm = zero16;
  const uint4* qptr = &qh[(pbase + cl)*2 + hl];
  #pragma unroll 2
  for (int ct = 0; ct < 128; ++ct) {
    bf16x8 bQ = *(const bf16x8*)qptr;
    qptr += 64;                      // 32 points x 2 uint4
    f32x16 c = __builtin_amdgcn_mfma_f32_32x32x16_bf16(aK, bQ, zero16, 0, 0, 0);
    #pragma unroll
    for (int r = 0; r < 16; ++r) lm[r] = fmaxf(lm[r], c[r]);
  }
  #pragma unroll
  for (int off = 1; off <= 16; off <<= 1) {
    #pragma unroll
    for (int r = 0; r < 16; ++r) lm[r] = fmaxf(lm[r], __shfl_xor(lm[r], off));
  }
  if (cl == 0) {
    #pragma unroll
    for (int r = 0; r < 16; ++r)
      pmax[pbase + n0 + (r & 3) + 8*(r >> 2) + 4*hl] = lm[r];
  }
}

// ---- k5pv: pass 2 — fixed-M PV loop (no shfl, no rescale, no branch) -------
// QK: A = Q-side [qh;ql], B1=[kh;kh], B2=[kl;kl] -> exact. C: col=lane&15=n,
// row=(lane>>4)*4+reg=m. pw = 2^(c - Mrow), Mrow per n from pass 1.
// PV: mfma_f32_16x16x16f16(A=vfh rows (nl), B=pw, acc); rows 4-15 of vfh are
// reserved garbage -> pollute only unread C rows.
__global__ __launch_bounds__(128, 8) void k5pv(
    const uint4* __restrict__ qh, const uint4* __restrict__ ql,
    const uint4* __restrict__ kh, const uint4* __restrict__ kl,
    const _Float16* __restrict__ vfh, const float* __restrict__ pmax,
    float* __restrict__ pl, float* __restrict__ pa0,
    float* __restrict__ pa1, float* __restrict__ pa2) {
  int tx = threadIdx.x;
  int cb = blockIdx.x & 3;
  int rb = blockIdx.x >> 2;
  int b  = rb >> 7;
  int rc = rb & 127;
  int w = tx >> 6, lane = tx & 63;
  int nl = lane & 15, g = lane >> 4, g1 = g & 1;
  int n0 = rc*32 + w*16;
  size_t pbase = (size_t)b*4096;
  size_t kp2 = (pbase + n0 + nl)*2;
  bf16x8 bKh = *(const bf16x8*)&kh[kp2 + g1];
  bf16x8 bKl = *(const bf16x8*)&kl[kp2 + g1];
  float Mrow = pmax[pbase + n0 + nl];
  f32x4 zero4 = {0.f, 0.f, 0.f, 0.f};
  f32x4 acc = {0.f, 0.f, 0.f, 0.f};       // rows a0,a1,a2,l
  size_t cbase = pbase + (size_t)cb*1024;
  const uint4* qptr = ((g < 2) ? qh : ql) + (cbase + nl)*2 + g1;
  const _Float16* vptr = vfh + (size_t)nl*32768 + cbase + g*4;
  #pragma unroll 4
  for (int ct = 0; ct < 64; ++ct) {
    bf16x8 aQ = *(const bf16x8*)qptr;
    qptr += 32;                           // 16 points x 2 uint4
    f32x4 c = __builtin_amdgcn_mfma_f32_16x16x32_bf16(aQ, bKh, zero4, 0, 0, 0);
    c = __builtin_amdgcn_mfma_f32_16x16x32_bf16(aQ, bKl, c, 0, 0, 0);
    union { fp16x2 h2[2]; f16x4 v4; } pw;
    pw.h2[0] = __builtin_amdgcn_cvt_pkrtz(EXP2F(c[0] - Mrow), EXP2F(c[1] - Mrow));
    pw.h2[1] = __builtin_amdgcn_cvt_pkrtz(EXP2F(c[2] - Mrow), EXP2F(c[3] - Mrow));
    f16x4 av = *(const f16x4*)vptr;
    vptr += 16;
    acc = __builtin_amdgcn_mfma_f32_16x16x16f16(av, pw.v4, acc, 0, 0, 0);
  }
  if (lane < 16) {
    size_t base = (size_t)cb*32768 + pbase + n0 + lane;
    pl[base] = acc[3];
    pa0[base] = acc[0]; pa1[base] = acc[1]; pa2[base] = acc[2];
  }
}

// ---- k6: pure-sum merge of 4 column chunks + epilogue ----------------------
__global__ __launch_bounds__(256) void k6_merge(
    const float* __restrict__ pl, const float* __restrict__ pa0,
    const float* __restrict__ pa1, const float* __restrict__ pa2,
    const float* __restrict__ x, const float* __restrict__ alpha,
    float* __restrict__ out) {
  int row = blockIdx.x*256 + threadIdx.x;   // 0..32767
  float L  = pl[row]  + pl[32768+row]  + pl[2*32768+row]  + pl[3*32768+row];
  float A0 = pa0[row] + pa0[32768+row] + pa0[2*32768+row] + pa0[3*32768+row];
  float A1 = pa1[row] + pa1[32768+row] + pa1[2*32768+row] + pa1[3*32768+row];
  float A2 = pa2[row] + pa2[32768+row] + pa2[2*32768+row] + pa2[3*32768+row];
  int b = row >> 12, n = row & 4095;
  float inv = 1.f / L, al = alpha[0];
  out[(size_t)(b*3+0)*NN + n] = fmaf(al, A0*inv, x[(size_t)(b*3+0)*NN + n]);
  out[(size_t)(b*3+1)*NN + n] = fmaf(al, A1*inv, x[(size_t)(b*3+1)*NN + n]);
  out[(size_t)(b*3+2)*NN + n] = fmaf(al, A2*inv, x[(size_t)(b*3+2)*NN + n]);
}

extern "C" void kernel_launch(void* const* d_in, const int* in_sizes, int n_in,
                              void* d_out, int out_size, void* d_ws, size_t ws_size,
                              hipStream_t stream) {
  const float* x    = (const float*)d_in[0];
  const float* w1   = (const float*)d_in[1];
  const float* g1   = (const float*)d_in[2];
  const float* b1   = (const float*)d_in[3];
  const float* w2   = (const float*)d_in[4];
  const float* wq   = (const float*)d_in[5];
  const float* g2   = (const float*)d_in[6];
  const float* b2   = (const float*)d_in[7];
  const float* wk   = (const float*)d_in[8];
  const float* g3   = (const float*)d_in[9];
  const float* b3   = (const float*)d_in[10];
  const float* wv   = (const float*)d_in[11];
  const float* g4   = (const float*)d_in[12];
  const float* b4   = (const float*)d_in[13];
  const float* alpha= (const float*)d_in[14];
  float* out = (float*)d_out;
  float* ws  = (float*)d_ws;

  float* qpT = ws + OFF_QPT;
  float* kpT = ws + OFF_KPT;
  float* vpT = ws + OFF_VPT;
  float* wt2 = ws + OFF_WT2;
  float* xp  = ws + OFF_XP;
  float* bst = ws + OFF_BS;
  uint4* qhb = (uint4*)(ws + OFF_QH);
  uint4* qlb = (uint4*)(ws + OFF_QL);
  uint4* khb = (uint4*)(ws + OFF_KH);
  uint4* klb = (uint4*)(ws + OFF_KL);
  _Float16* vfh = (_Float16*)(ws + OFF_VFH);
  float* pls = ws + OFF_PL;
  float* pa0 = ws + OFF_PA0;
  float* pa1 = ws + OFF_PA1;
  float* pa2 = ws + OFF_PA2;
  float* pmx = ws + OFF_PMX;

  kA_mom_wcomb<<<129, 256, 0, stream>>>(x, xp, w2, wq, wk, wv, wt2);
  kB_qkv<<<256, 128, 0, stream>>>(x, xp, w1, g1, b1, wt2, qpT, kpT, vpT, bst);
  kC_prep<<<128, 256, 0, stream>>>(qpT, kpT, vpT, bst, g2, b2, g3, b3, g4, b4,
                                   qhb, qlb, khb, klb, vfh);
  k5max<<<256, 256, 0, stream>>>(qhb, khb, pmx);
  k5pv<<<4096, 128, 0, stream>>>(qhb, qlb, khb, klb, vfh, pmx, pls, pa0, pa1, pa2);
  k6_merge<<<128, 256, 0, stream>>>(pls, pa0, pa1, pa2, x, alpha, out);
}

// Round 15
// 101.596 us; speedup vs baseline: 1.5329x; 1.5329x over previous
//
#include <hip/hip_runtime.h>

#define EPS 1e-5f
constexpr int NN = 4096;
constexpr float INV_CNT = 1.0f / (8.0f * 4096.0f);
constexpr float LOG2E = 1.44269504f;

typedef __attribute__((ext_vector_type(8))) short bf16x8;
typedef __attribute__((ext_vector_type(4))) float f32x4;
typedef __attribute__((ext_vector_type(16))) float f32x16;
typedef __attribute__((ext_vector_type(4))) _Float16 f16x4;
typedef __fp16 fp16x2 __attribute__((ext_vector_type(2)));

#if __has_builtin(__builtin_amdgcn_exp2f)
#define EXP2F(x) __builtin_amdgcn_exp2f(x)
#else
#define EXP2F(x) exp2f(x)
#endif

// workspace layout (float offsets)
constexpr size_t OFF_QPT = 0;        // 524288
constexpr size_t OFF_KPT = 524288;   // 524288
constexpr size_t OFF_VPT = 1048576;  // 131072
constexpr size_t OFF_WT2 = 1179648;  // 2304
constexpr size_t OFF_XP  = 1181952;  // 1152
constexpr size_t OFF_BS  = 1183104;  // 17920
constexpr size_t OFF_QH  = 1201024;  // 262144
constexpr size_t OFF_QL  = 1463168;  // 262144
constexpr size_t OFF_KH  = 1725312;  // 262144
constexpr size_t OFF_KL  = 1987456;  // 262144
constexpr size_t OFF_VFH = 2249600;  // 262144 (16 rows x 32768 fp16; rows 0-3 live)
constexpr size_t OFF_PL  = 2511744;  // 8*32768 = 262144
constexpr size_t OFF_PA0 = 2773888;  // 262144
constexpr size_t OFF_PA1 = 3036032;  // 262144
constexpr size_t OFF_PA2 = 3298176;  // 262144
constexpr size_t OFF_PMX = 3560320;  // 4*32768 = 131072; end 3691392 = 14.8 MB

// ---- kA: blocks 0-127: x moments; block 128: combined weights --------------
__global__ __launch_bounds__(256) void kA_mom_wcomb(
    const float* __restrict__ x, float* __restrict__ xpart,
    const float* __restrict__ w2, const float* __restrict__ wq,
    const float* __restrict__ wk, const float* __restrict__ wv,
    float* __restrict__ wt2) {
  __shared__ float w2s[8192];
  __shared__ float wr[4480];
  __shared__ float sred[36];
  int tx = threadIdx.x;
  if (blockIdx.x < 128) {
    int idx = blockIdx.x * 256 + tx;
    int b = idx >> 12, n = idx & 4095;
    float x0 = x[(size_t)(b*3+0)*NN + n];
    float x1 = x[(size_t)(b*3+1)*NN + n];
    float x2 = x[(size_t)(b*3+2)*NN + n];
    float m[9] = {x0, x1, x2, x0*x0, x0*x1, x0*x2, x1*x1, x1*x2, x2*x2};
    #pragma unroll
    for (int off = 32; off; off >>= 1) {
      #pragma unroll
      for (int j = 0; j < 9; ++j) m[j] += __shfl_xor(m[j], off);
    }
    int w = tx >> 6;
    if ((tx & 63) == 0) {
      #pragma unroll
      for (int j = 0; j < 9; ++j) sred[w*9+j] = m[j];
    }
    __syncthreads();
    if (tx < 9) xpart[tx*128 + blockIdx.x] = sred[tx] + sred[9+tx] + sred[18+tx] + sred[27+tx];
  } else {
    for (int i = tx; i < 8192; i += 256) w2s[i] = w2[i];
    for (int i = tx; i < 2048; i += 256) { wr[i] = wq[i]; wr[2048+i] = wk[i]; }
    for (int i = tx; i < 384; i += 256) wr[4096+i] = wv[i];
    __syncthreads();
    for (int e = tx; e < 2240; e += 256) {
      int j = e >> 6, c = e & 63;
      float s = 0.f;
      #pragma unroll 4
      for (int o = 0; o < 128; ++o) s = fmaf(wr[j*128+o], w2s[o*64+c], s);
      wt2[c*36 + j] = s;
    }
  }
}

// ---- kB: (f1 fused) per point -> qa/ka/va + block-partial stats ------------
__global__ __launch_bounds__(128) void kB_qkv(
    const float* __restrict__ x, const float* __restrict__ xpart,
    const float* __restrict__ w1, const float* __restrict__ g1,
    const float* __restrict__ b1, const float* __restrict__ wt2,
    float* __restrict__ qpT, float* __restrict__ kpT, float* __restrict__ vpT,
    float* __restrict__ bs) {
  __shared__ float4 w1s[64];
  __shared__ float4 wt2s[576];
  __shared__ float sred[140];
  __shared__ float mom[9];
  int tx = threadIdx.x;
  for (int i = tx; i < 576; i += 128) wt2s[i] = ((const float4*)wt2)[i];
  if (tx < 9) {
    float acc = 0.f;
    #pragma unroll 8
    for (int i = 0; i < 128; ++i) acc += xpart[tx*128 + i];
    mom[tx] = acc * INV_CNT;
  }
  __syncthreads();
  if (tx < 64) {
    int c = tx;
    float a = w1[c*3], b_ = w1[c*3+1], d = w1[c*3+2];
    float mean = a*mom[0] + b_*mom[1] + d*mom[2];
    float e2 = a*a*mom[3] + b_*b_*mom[6] + d*d*mom[8]
             + 2.f*(a*b_*mom[4] + a*d*mom[5] + b_*d*mom[7]);
    float sc = g1[c] * rsqrtf(e2 - mean*mean + EPS);
    w1s[c] = make_float4(a*sc, b_*sc, d*sc, fmaf(-mean, sc, b1[c]));
  }
  __syncthreads();
  int idx = blockIdx.x*128 + tx;
  int b = idx >> 12, n = idx & 4095;
  float x0 = x[(size_t)(b*3+0)*NN + n];
  float x1 = x[(size_t)(b*3+1)*NN + n];
  float x2 = x[(size_t)(b*3+2)*NN + n];
  float qa[16] = {}, ka[16] = {};
  float va0 = 0.f, va1 = 0.f, va2 = 0.f;
  #pragma unroll 4
  for (int c = 0; c < 64; ++c) {
    float4 w = w1s[c];
    float h = fmaf(w.x, x0, fmaf(w.y, x1, fmaf(w.z, x2, w.w)));
    h = h > 0.f ? h : 0.2f*h;
    #pragma unroll
    for (int j = 0; j < 4; ++j) {
      float4 A = wt2s[c*9 + j];
      qa[4*j+0] = fmaf(A.x, h, qa[4*j+0]);
      qa[4*j+1] = fmaf(A.y, h, qa[4*j+1]);
      qa[4*j+2] = fmaf(A.z, h, qa[4*j+2]);
      qa[4*j+3] = fmaf(A.w, h, qa[4*j+3]);
      float4 B = wt2s[c*9 + 4 + j];
      ka[4*j+0] = fmaf(B.x, h, ka[4*j+0]);
      ka[4*j+1] = fmaf(B.y, h, ka[4*j+1]);
      ka[4*j+2] = fmaf(B.z, h, ka[4*j+2]);
      ka[4*j+3] = fmaf(B.w, h, ka[4*j+3]);
    }
    float4 V = wt2s[c*9 + 8];
    va0 = fmaf(V.x, h, va0); va1 = fmaf(V.y, h, va1); va2 = fmaf(V.z, h, va2);
  }
  float4* qo = (float4*)(qpT + (size_t)idx*16);
  float4* ko = (float4*)(kpT + (size_t)idx*16);
  #pragma unroll
  for (int j = 0; j < 4; ++j) {
    qo[j] = make_float4(qa[4*j], qa[4*j+1], qa[4*j+2], qa[4*j+3]);
    ko[j] = make_float4(ka[4*j], ka[4*j+1], ka[4*j+2], ka[4*j+3]);
  }
  ((float4*)vpT)[idx] = make_float4(va0, va1, va2, 0.f);
  int w = tx >> 6;
  bool lead = ((tx & 63) == 0);
  #pragma unroll
  for (int d = 0; d < 16; ++d) {
    float s = qa[d], q = qa[d]*qa[d];
    #pragma unroll
    for (int off = 32; off; off >>= 1) { s += __shfl_xor(s, off); q += __shfl_xor(q, off); }
    if (lead) { sred[w*70 + d] = s; sred[w*70 + 16 + d] = q; }
    s = ka[d]; q = ka[d]*ka[d];
    #pragma unroll
    for (int off = 32; off; off >>= 1) { s += __shfl_xor(s, off); q += __shfl_xor(q, off); }
    if (lead) { sred[w*70 + 32 + d] = s; sred[w*70 + 48 + d] = q; }
  }
  float vv[3] = {va0, va1, va2};
  #pragma unroll
  for (int d = 0; d < 3; ++d) {
    float s = vv[d], q = vv[d]*vv[d];
    #pragma unroll
    for (int off = 32; off; off >>= 1) { s += __shfl_xor(s, off); q += __shfl_xor(q, off); }
    if (lead) { sred[w*70 + 64 + d] = s; sred[w*70 + 67 + d] = q; }
  }
  __syncthreads();
  if (tx < 70)
    bs[tx*256 + blockIdx.x] = sred[tx] + sred[70+tx];
}

// ---- kC: (f2 fused) BN+ReLU, q scaled by log2e, hi/lo split, v->fp16 -------
__global__ __launch_bounds__(256) void kC_prep(
    const float* __restrict__ qpT, const float* __restrict__ kpT,
    const float* __restrict__ vpT, const float* __restrict__ bs,
    const float* __restrict__ g2, const float* __restrict__ b2,
    const float* __restrict__ g3, const float* __restrict__ b3,
    const float* __restrict__ g4, const float* __restrict__ b4,
    uint4* __restrict__ qh, uint4* __restrict__ ql,
    uint4* __restrict__ kh, uint4* __restrict__ kl,
    _Float16* __restrict__ vfh) {
  __shared__ float tot[70];
  __shared__ float spr[70];
  int tx = threadIdx.x;
  if (tx < 70) {
    float acc = 0.f;
    #pragma unroll 8
    for (int i = 0; i < 256; ++i) acc += bs[tx*256 + i];
    tot[tx] = acc * INV_CNT;
  }
  __syncthreads();
  if (tx < 16) {
    float mean = tot[tx], var = tot[16+tx] - mean*mean;
    float sc = g2[tx]*rsqrtf(var + EPS);
    spr[tx] = sc * LOG2E;
    spr[16+tx] = fmaf(-mean, sc, b2[tx]) * LOG2E;
  } else if (tx < 32) {
    int d = tx-16;
    float mean = tot[32+d], var = tot[48+d] - mean*mean;
    float sc = g3[d]*rsqrtf(var + EPS);
    spr[32+d] = sc; spr[48+d] = fmaf(-mean, sc, b3[d]);
  } else if (tx < 35) {
    int d = tx-32;
    float mean = tot[64+d], var = tot[67+d] - mean*mean;
    float sc = g4[d]*rsqrtf(var + EPS);
    spr[64+d] = sc; spr[67+d] = fmaf(-mean, sc, b4[d]);
  }
  __syncthreads();
  int p = blockIdx.x*256 + tx;
  float qv[16], kv[16];
  const float4* q4 = (const float4*)(qpT + (size_t)p*16);
  const float4* k4p = (const float4*)(kpT + (size_t)p*16);
  #pragma unroll
  for (int j = 0; j < 4; ++j) {
    float4 tq = q4[j], tk = k4p[j];
    qv[4*j] = tq.x; qv[4*j+1] = tq.y; qv[4*j+2] = tq.z; qv[4*j+3] = tq.w;
    kv[4*j] = tk.x; kv[4*j+1] = tk.y; kv[4*j+2] = tk.z; kv[4*j+3] = tk.w;
  }
  #pragma unroll
  for (int d = 0; d < 16; ++d) {
    qv[d] = fmaxf(fmaf(qv[d], spr[d],    spr[16+d]), 0.f);
    kv[d] = fmaxf(fmaf(kv[d], spr[32+d], spr[48+d]), 0.f);
  }
  unsigned qhw[8], qlw[8], khw[8], klw[8];
  #pragma unroll
  for (int j = 0; j < 8; ++j) {
    unsigned u0 = __float_as_uint(qv[2*j]),   u1 = __float_as_uint(qv[2*j+1]);
    unsigned h0 = u0 & 0xFFFF0000u, h1 = u1 & 0xFFFF0000u;
    float l0 = qv[2*j] - __uint_as_float(h0);
    float l1 = qv[2*j+1] - __uint_as_float(h1);
    qhw[j] = (h0 >> 16) | h1;
    qlw[j] = (__float_as_uint(l0) >> 16) | (__float_as_uint(l1) & 0xFFFF0000u);
    u0 = __float_as_uint(kv[2*j]); u1 = __float_as_uint(kv[2*j+1]);
    h0 = u0 & 0xFFFF0000u; h1 = u1 & 0xFFFF0000u;
    l0 = kv[2*j] - __uint_as_float(h0);
    l1 = kv[2*j+1] - __uint_as_float(h1);
    khw[j] = (h0 >> 16) | h1;
    klw[j] = (__float_as_uint(l0) >> 16) | (__float_as_uint(l1) & 0xFFFF0000u);
  }
  qh[(size_t)p*2+0] = make_uint4(qhw[0], qhw[1], qhw[2], qhw[3]);
  qh[(size_t)p*2+1] = make_uint4(qhw[4], qhw[5], qhw[6], qhw[7]);
  ql[(size_t)p*2+0] = make_uint4(qlw[0], qlw[1], qlw[2], qlw[3]);
  ql[(size_t)p*2+1] = make_uint4(qlw[4], qlw[5], qlw[6], qlw[7]);
  kh[(size_t)p*2+0] = make_uint4(khw[0], khw[1], khw[2], khw[3]);
  kh[(size_t)p*2+1] = make_uint4(khw[4], khw[5], khw[6], khw[7]);
  kl[(size_t)p*2+0] = make_uint4(klw[0], klw[1], klw[2], klw[3]);
  kl[(size_t)p*2+1] = make_uint4(klw[4], klw[5], klw[6], klw[7]);
  float4 vv = ((const float4*)vpT)[p];
  vfh[0*32768 + p] = (_Float16)fmaxf(fmaf(vv.x, spr[64], spr[67]), 0.f);
  vfh[1*32768 + p] = (_Float16)fmaxf(fmaf(vv.y, spr[65], spr[68]), 0.f);
  vfh[2*32768 + p] = (_Float16)fmaxf(fmaf(vv.z, spr[66], spr[69]), 0.f);
  vfh[3*32768 + p] = (_Float16)1.0f;
}

// ---- k5max: pass 1 — hi-only per-row max, 32x32x16, 4-way column split -----
// C layout (m74/m101): col=lane&31 (q pt m), row=(reg&3)+8*(reg>>2)+4*(lane>>5).
// blk: cc = blk&3 (1024-col chunk), rc = (blk>>2)&31, b = blk>>7.
__global__ __launch_bounds__(256, 4) void k5max(
    const uint4* __restrict__ qh, const uint4* __restrict__ kh,
    float* __restrict__ pmax2) {
  int tx = threadIdx.x;
  int cc = blockIdx.x & 3;
  int rc = (blockIdx.x >> 2) & 31;
  int b  = blockIdx.x >> 7;
  int w = tx >> 6, lane = tx & 63;
  int cl = lane & 31, hl = lane >> 5;
  int n0 = rc*128 + w*32;
  size_t pbase = (size_t)b*4096;
  bf16x8 aK = *(const bf16x8*)&kh[(pbase + n0 + cl)*2 + hl];
  f32x16 zero16;
  #pragma unroll
  for (int r = 0; r < 16; ++r) zero16[r] = 0.f;
  f32x16 lm = zero16;
  const uint4* qptr = &qh[(pbase + (size_t)cc*1024 + cl)*2 + hl];
  #pragma unroll 2
  for (int ct = 0; ct < 32; ++ct) {
    bf16x8 bQ = *(const bf16x8*)qptr;
    qptr += 64;                      // 32 points x 2 uint4
    f32x16 c = __builtin_amdgcn_mfma_f32_32x32x16_bf16(aK, bQ, zero16, 0, 0, 0);
    #pragma unroll
    for (int r = 0; r < 16; ++r) lm[r] = fmaxf(lm[r], c[r]);
  }
  #pragma unroll
  for (int off = 1; off <= 16; off <<= 1) {
    #pragma unroll
    for (int r = 0; r < 16; ++r) lm[r] = fmaxf(lm[r], __shfl_xor(lm[r], off));
  }
  if (cl == 0) {
    #pragma unroll
    for (int r = 0; r < 16; ++r)
      pmax2[(size_t)cc*32768 + pbase + n0 + (r & 3) + 8*(r >> 2) + 4*hl] = lm[r];
  }
}

// ---- k5pv: pass 2 — 4 row-tiles/wave (Q/V reuse x4), fixed-M PV loop -------
// blk: cb = blk&7 (512-col chunk), rb = blk>>3: b = rb>>5, rc = rb&31.
// wave w: rows n0 = rc*128 + w*64, tiles r at n0+r*16.
__global__ __launch_bounds__(128, 4) void k5pv(
    const uint4* __restrict__ qh, const uint4* __restrict__ ql,
    const uint4* __restrict__ kh, const uint4* __restrict__ kl,
    const _Float16* __restrict__ vfh, const float* __restrict__ pmax2,
    float* __restrict__ pl, float* __restrict__ pa0,
    float* __restrict__ pa1, float* __restrict__ pa2) {
  int tx = threadIdx.x;
  int cb = blockIdx.x & 7;
  int rb = blockIdx.x >> 3;
  int b  = rb >> 5;
  int rc = rb & 31;
  int w = tx >> 6, lane = tx & 63;
  int nl = lane & 15, g = lane >> 4, g1 = g & 1;
  int n0 = rc*128 + w*64;
  size_t pbase = (size_t)b*4096;
  bf16x8 bKh[4], bKl[4];
  float Mrow[4];
  #pragma unroll
  for (int r = 0; r < 4; ++r) {
    size_t kp2 = (pbase + n0 + r*16 + nl)*2;
    bKh[r] = *(const bf16x8*)&kh[kp2 + g1];
    bKl[r] = *(const bf16x8*)&kl[kp2 + g1];
    size_t mi = pbase + n0 + r*16 + nl;
    float m01 = fmaxf(pmax2[mi], pmax2[32768 + mi]);
    float m23 = fmaxf(pmax2[2*32768 + mi], pmax2[3*32768 + mi]);
    Mrow[r] = fmaxf(m01, m23);
  }
  f32x4 zero4 = {0.f, 0.f, 0.f, 0.f};
  f32x4 acc0 = zero4, acc1 = zero4, acc2 = zero4, acc3 = zero4;
  size_t cbase = pbase + (size_t)cb*512;
  const uint4* qptr = ((g < 2) ? qh : ql) + (cbase + nl)*2 + g1;
  const _Float16* vptr = vfh + (size_t)nl*32768 + cbase + g*4;
  bool vload = (nl < 4);
  f16x4 zeroh = {(_Float16)0.f, (_Float16)0.f, (_Float16)0.f, (_Float16)0.f};
  #pragma unroll 2
  for (int ct = 0; ct < 32; ++ct) {
    bf16x8 aQ = *(const bf16x8*)qptr;
    qptr += 32;                           // 16 points x 2 uint4
    f16x4 av = zeroh;
    if (vload) av = *(const f16x4*)vptr;
    vptr += 16;
    #pragma unroll
    for (int r = 0; r < 4; ++r) {
      f32x4 c = __builtin_amdgcn_mfma_f32_16x16x32_bf16(aQ, bKh[r], zero4, 0, 0, 0);
      c = __builtin_amdgcn_mfma_f32_16x16x32_bf16(aQ, bKl[r], c, 0, 0, 0);
      union { fp16x2 h2[2]; f16x4 v4; } pw;
      pw.h2[0] = __builtin_amdgcn_cvt_pkrtz(EXP2F(c[0] - Mrow[r]), EXP2F(c[1] - Mrow[r]));
      pw.h2[1] = __builtin_amdgcn_cvt_pkrtz(EXP2F(c[2] - Mrow[r]), EXP2F(c[3] - Mrow[r]));
      f32x4 t = __builtin_amdgcn_mfma_f32_16x16x16f16(av, pw.v4, zero4, 0, 0, 0);
      if (r == 0) acc0 += t; else if (r == 1) acc1 += t;
      else if (r == 2) acc2 += t; else acc3 += t;
    }
  }
  if (lane < 16) {
    size_t base = (size_t)cb*32768 + pbase + n0 + lane;
    pl[base]        = acc0[3]; pa0[base]        = acc0[0]; pa1[base]        = acc0[1]; pa2[base]        = acc0[2];
    pl[base + 16]   = acc1[3]; pa0[base + 16]   = acc1[0]; pa1[base + 16]   = acc1[1]; pa2[base + 16]   = acc1[2];
    pl[base + 32]   = acc2[3]; pa0[base + 32]   = acc2[0]; pa1[base + 32]   = acc2[1]; pa2[base + 32]   = acc2[2];
    pl[base + 48]   = acc3[3]; pa0[base + 48]   = acc3[0]; pa1[base + 48]   = acc3[1]; pa2[base + 48]   = acc3[2];
  }
}

// ---- k6: pure-sum merge of 8 column chunks + epilogue ----------------------
__global__ __launch_bounds__(256) void k6_merge(
    const float* __restrict__ pl, const float* __restrict__ pa0,
    const float* __restrict__ pa1, const float* __restrict__ pa2,
    const float* __restrict__ x, const float* __restrict__ alpha,
    float* __restrict__ out) {
  int row = blockIdx.x*256 + threadIdx.x;   // 0..32767
  float L = 0.f, A0 = 0.f, A1 = 0.f, A2 = 0.f;
  #pragma unroll
  for (int cb = 0; cb < 8; ++cb) {
    size_t i = (size_t)cb*32768 + row;
    L += pl[i]; A0 += pa0[i]; A1 += pa1[i]; A2 += pa2[i];
  }
  int b = row >> 12, n = row & 4095;
  float inv = 1.f / L, al = alpha[0];
  out[(size_t)(b*3+0)*NN + n] = fmaf(al, A0*inv, x[(size_t)(b*3+0)*NN + n]);
  out[(size_t)(b*3+1)*NN + n] = fmaf(al, A1*inv, x[(size_t)(b*3+1)*NN + n]);
  out[(size_t)(b*3+2)*NN + n] = fmaf(al, A2*inv, x[(size_t)(b*3+2)*NN + n]);
}

extern "C" void kernel_launch(void* const* d_in, const int* in_sizes, int n_in,
                              void* d_out, int out_size, void* d_ws, size_t ws_size,
                              hipStream_t stream) {
  const float* x    = (const float*)d_in[0];
  const float* w1   = (const float*)d_in[1];
  const float* g1   = (const float*)d_in[2];
  const float* b1   = (const float*)d_in[3];
  const float* w2   = (const float*)d_in[4];
  const float* wq   = (const float*)d_in[5];
  const float* g2   = (const float*)d_in[6];
  const float* b2   = (const float*)d_in[7];
  const float* wk   = (const float*)d_in[8];
  const float* g3   = (const float*)d_in[9];
  const float* b3   = (const float*)d_in[10];
  const float* wv   = (const float*)d_in[11];
  const float* g4   = (const float*)d_in[12];
  const float* b4   = (const float*)d_in[13];
  const float* alpha= (const float*)d_in[14];
  float* out = (float*)d_out;
  float* ws  = (float*)d_ws;

  float* qpT = ws + OFF_QPT;
  float* kpT = ws + OFF_KPT;
  float* vpT = ws + OFF_VPT;
  float* wt2 = ws + OFF_WT2;
  float* xp  = ws + OFF_XP;
  float* bst = ws + OFF_BS;
  uint4* qhb = (uint4*)(ws + OFF_QH);
  uint4* qlb = (uint4*)(ws + OFF_QL);
  uint4* khb = (uint4*)(ws + OFF_KH);
  uint4* klb = (uint4*)(ws + OFF_KL);
  _Float16* vfh = (_Float16*)(ws + OFF_VFH);
  float* pls = ws + OFF_PL;
  float* pa0 = ws + OFF_PA0;
  float* pa1 = ws + OFF_PA1;
  float* pa2 = ws + OFF_PA2;
  float* pmx = ws + OFF_PMX;

  kA_mom_wcomb<<<129, 256, 0, stream>>>(x, xp, w2, wq, wk, wv, wt2);
  kB_qkv<<<256, 128, 0, stream>>>(x, xp, w1, g1, b1, wt2, qpT, kpT, vpT, bst);
  kC_prep<<<128, 256, 0, stream>>>(qpT, kpT, vpT, bst, g2, b2, g3, b3, g4, b4,
                                   qhb, qlb, khb, klb, vfh);
  k5max<<<1024, 256, 0, stream>>>(qhb, khb, pmx);
  k5pv<<<2048, 128, 0, stream>>>(qhb, qlb, khb, klb, vfh, pmx, pls, pa0, pa1, pa2);
  k6_merge<<<128, 256, 0, stream>>>(pls, pa0, pa1, pa2, x, alpha, out);
}

// Round 16
// 97.960 us; speedup vs baseline: 1.5898x; 1.0371x over previous
//
#include <hip/hip_runtime.h>

#define EPS 1e-5f
constexpr int NN = 4096;
constexpr float INV_CNT = 1.0f / (8.0f * 4096.0f);
constexpr float LOG2E = 1.44269504f;

typedef __attribute__((ext_vector_type(8))) short bf16x8;
typedef __attribute__((ext_vector_type(4))) float f32x4;
typedef __attribute__((ext_vector_type(16))) float f32x16;
typedef __attribute__((ext_vector_type(4))) _Float16 f16x4;
typedef __fp16 fp16x2 __attribute__((ext_vector_type(2)));

#if __has_builtin(__builtin_amdgcn_exp2f)
#define EXP2F(x) __builtin_amdgcn_exp2f(x)
#else
#define EXP2F(x) exp2f(x)
#endif

// workspace layout (float offsets)
constexpr size_t OFF_QPT = 0;        // 524288
constexpr size_t OFF_KPT = 524288;   // 524288
constexpr size_t OFF_VPT = 1048576;  // 131072
constexpr size_t OFF_WT2 = 1179648;  // 2304
constexpr size_t OFF_XP  = 1181952;  // 1152
constexpr size_t OFF_BS  = 1183104;  // 17920
constexpr size_t OFF_QH  = 1201024;  // 262144
constexpr size_t OFF_QL  = 1463168;  // 262144
constexpr size_t OFF_KH  = 1725312;  // 262144
constexpr size_t OFF_KL  = 1987456;  // 262144
constexpr size_t OFF_VFH = 2249600;  // 262144 (16 rows x 32768 fp16; rows 0-3 live)
constexpr size_t OFF_PL  = 2511744;  // 8*32768 = 262144
constexpr size_t OFF_PA0 = 2773888;  // 262144
constexpr size_t OFF_PA1 = 3036032;  // 262144
constexpr size_t OFF_PA2 = 3298176;  // 262144
constexpr size_t OFF_PMX = 3560320;  // 4*32768 = 131072; end 3691392 = 14.8 MB

// ---- kA: blocks 0-127: x moments; block 128: combined weights --------------
__global__ __launch_bounds__(256) void kA_mom_wcomb(
    const float* __restrict__ x, float* __restrict__ xpart,
    const float* __restrict__ w2, const float* __restrict__ wq,
    const float* __restrict__ wk, const float* __restrict__ wv,
    float* __restrict__ wt2) {
  __shared__ float w2s[8192];
  __shared__ float wr[4480];
  __shared__ float sred[36];
  int tx = threadIdx.x;
  if (blockIdx.x < 128) {
    int idx = blockIdx.x * 256 + tx;
    int b = idx >> 12, n = idx & 4095;
    float x0 = x[(size_t)(b*3+0)*NN + n];
    float x1 = x[(size_t)(b*3+1)*NN + n];
    float x2 = x[(size_t)(b*3+2)*NN + n];
    float m[9] = {x0, x1, x2, x0*x0, x0*x1, x0*x2, x1*x1, x1*x2, x2*x2};
    #pragma unroll
    for (int off = 32; off; off >>= 1) {
      #pragma unroll
      for (int j = 0; j < 9; ++j) m[j] += __shfl_xor(m[j], off);
    }
    int w = tx >> 6;
    if ((tx & 63) == 0) {
      #pragma unroll
      for (int j = 0; j < 9; ++j) sred[w*9+j] = m[j];
    }
    __syncthreads();
    if (tx < 9) xpart[tx*128 + blockIdx.x] = sred[tx] + sred[9+tx] + sred[18+tx] + sred[27+tx];
  } else {
    for (int i = tx; i < 8192; i += 256) w2s[i] = w2[i];
    for (int i = tx; i < 2048; i += 256) { wr[i] = wq[i]; wr[2048+i] = wk[i]; }
    for (int i = tx; i < 384; i += 256) wr[4096+i] = wv[i];
    __syncthreads();
    for (int e = tx; e < 2240; e += 256) {
      int j = e >> 6, c = e & 63;
      float s = 0.f;
      #pragma unroll 4
      for (int o = 0; o < 128; ++o) s = fmaf(wr[j*128+o], w2s[o*64+c], s);
      wt2[c*36 + j] = s;
    }
  }
}

// ---- kB: (f1 fused) per point -> qa/ka/va + block-partial stats ------------
__global__ __launch_bounds__(128) void kB_qkv(
    const float* __restrict__ x, const float* __restrict__ xpart,
    const float* __restrict__ w1, const float* __restrict__ g1,
    const float* __restrict__ b1, const float* __restrict__ wt2,
    float* __restrict__ qpT, float* __restrict__ kpT, float* __restrict__ vpT,
    float* __restrict__ bs) {
  __shared__ float4 w1s[64];
  __shared__ float4 wt2s[576];
  __shared__ float sred[140];
  __shared__ float mom[9];
  int tx = threadIdx.x;
  for (int i = tx; i < 576; i += 128) wt2s[i] = ((const float4*)wt2)[i];
  if (tx < 9) {
    float acc = 0.f;
    #pragma unroll 8
    for (int i = 0; i < 128; ++i) acc += xpart[tx*128 + i];
    mom[tx] = acc * INV_CNT;
  }
  __syncthreads();
  if (tx < 64) {
    int c = tx;
    float a = w1[c*3], b_ = w1[c*3+1], d = w1[c*3+2];
    float mean = a*mom[0] + b_*mom[1] + d*mom[2];
    float e2 = a*a*mom[3] + b_*b_*mom[6] + d*d*mom[8]
             + 2.f*(a*b_*mom[4] + a*d*mom[5] + b_*d*mom[7]);
    float sc = g1[c] * rsqrtf(e2 - mean*mean + EPS);
    w1s[c] = make_float4(a*sc, b_*sc, d*sc, fmaf(-mean, sc, b1[c]));
  }
  __syncthreads();
  int idx = blockIdx.x*128 + tx;
  int b = idx >> 12, n = idx & 4095;
  float x0 = x[(size_t)(b*3+0)*NN + n];
  float x1 = x[(size_t)(b*3+1)*NN + n];
  float x2 = x[(size_t)(b*3+2)*NN + n];
  float qa[16] = {}, ka[16] = {};
  float va0 = 0.f, va1 = 0.f, va2 = 0.f;
  #pragma unroll 4
  for (int c = 0; c < 64; ++c) {
    float4 w = w1s[c];
    float h = fmaf(w.x, x0, fmaf(w.y, x1, fmaf(w.z, x2, w.w)));
    h = h > 0.f ? h : 0.2f*h;
    #pragma unroll
    for (int j = 0; j < 4; ++j) {
      float4 A = wt2s[c*9 + j];
      qa[4*j+0] = fmaf(A.x, h, qa[4*j+0]);
      qa[4*j+1] = fmaf(A.y, h, qa[4*j+1]);
      qa[4*j+2] = fmaf(A.z, h, qa[4*j+2]);
      qa[4*j+3] = fmaf(A.w, h, qa[4*j+3]);
      float4 B = wt2s[c*9 + 4 + j];
      ka[4*j+0] = fmaf(B.x, h, ka[4*j+0]);
      ka[4*j+1] = fmaf(B.y, h, ka[4*j+1]);
      ka[4*j+2] = fmaf(B.z, h, ka[4*j+2]);
      ka[4*j+3] = fmaf(B.w, h, ka[4*j+3]);
    }
    float4 V = wt2s[c*9 + 8];
    va0 = fmaf(V.x, h, va0); va1 = fmaf(V.y, h, va1); va2 = fmaf(V.z, h, va2);
  }
  float4* qo = (float4*)(qpT + (size_t)idx*16);
  float4* ko = (float4*)(kpT + (size_t)idx*16);
  #pragma unroll
  for (int j = 0; j < 4; ++j) {
    qo[j] = make_float4(qa[4*j], qa[4*j+1], qa[4*j+2], qa[4*j+3]);
    ko[j] = make_float4(ka[4*j], ka[4*j+1], ka[4*j+2], ka[4*j+3]);
  }
  ((float4*)vpT)[idx] = make_float4(va0, va1, va2, 0.f);
  int w = tx >> 6;
  bool lead = ((tx & 63) == 0);
  #pragma unroll
  for (int d = 0; d < 16; ++d) {
    float s = qa[d], q = qa[d]*qa[d];
    #pragma unroll
    for (int off = 32; off; off >>= 1) { s += __shfl_xor(s, off); q += __shfl_xor(q, off); }
    if (lead) { sred[w*70 + d] = s; sred[w*70 + 16 + d] = q; }
    s = ka[d]; q = ka[d]*ka[d];
    #pragma unroll
    for (int off = 32; off; off >>= 1) { s += __shfl_xor(s, off); q += __shfl_xor(q, off); }
    if (lead) { sred[w*70 + 32 + d] = s; sred[w*70 + 48 + d] = q; }
  }
  float vv[3] = {va0, va1, va2};
  #pragma unroll
  for (int d = 0; d < 3; ++d) {
    float s = vv[d], q = vv[d]*vv[d];
    #pragma unroll
    for (int off = 32; off; off >>= 1) { s += __shfl_xor(s, off); q += __shfl_xor(q, off); }
    if (lead) { sred[w*70 + 64 + d] = s; sred[w*70 + 67 + d] = q; }
  }
  __syncthreads();
  if (tx < 70)
    bs[tx*256 + blockIdx.x] = sred[tx] + sred[70+tx];
}

// ---- kC: (f2 fused) BN+ReLU, q scaled by log2e, hi/lo split, v->fp16 -------
__global__ __launch_bounds__(256) void kC_prep(
    const float* __restrict__ qpT, const float* __restrict__ kpT,
    const float* __restrict__ vpT, const float* __restrict__ bs,
    const float* __restrict__ g2, const float* __restrict__ b2,
    const float* __restrict__ g3, const float* __restrict__ b3,
    const float* __restrict__ g4, const float* __restrict__ b4,
    uint4* __restrict__ qh, uint4* __restrict__ ql,
    uint4* __restrict__ kh, uint4* __restrict__ kl,
    _Float16* __restrict__ vfh) {
  __shared__ float tot[70];
  __shared__ float spr[70];
  int tx = threadIdx.x;
  if (tx < 70) {
    float acc = 0.f;
    #pragma unroll 8
    for (int i = 0; i < 256; ++i) acc += bs[tx*256 + i];
    tot[tx] = acc * INV_CNT;
  }
  __syncthreads();
  if (tx < 16) {
    float mean = tot[tx], var = tot[16+tx] - mean*mean;
    float sc = g2[tx]*rsqrtf(var + EPS);
    spr[tx] = sc * LOG2E;
    spr[16+tx] = fmaf(-mean, sc, b2[tx]) * LOG2E;
  } else if (tx < 32) {
    int d = tx-16;
    float mean = tot[32+d], var = tot[48+d] - mean*mean;
    float sc = g3[d]*rsqrtf(var + EPS);
    spr[32+d] = sc; spr[48+d] = fmaf(-mean, sc, b3[d]);
  } else if (tx < 35) {
    int d = tx-32;
    float mean = tot[64+d], var = tot[67+d] - mean*mean;
    float sc = g4[d]*rsqrtf(var + EPS);
    spr[64+d] = sc; spr[67+d] = fmaf(-mean, sc, b4[d]);
  }
  __syncthreads();
  int p = blockIdx.x*256 + tx;
  float qv[16], kv[16];
  const float4* q4 = (const float4*)(qpT + (size_t)p*16);
  const float4* k4p = (const float4*)(kpT + (size_t)p*16);
  #pragma unroll
  for (int j = 0; j < 4; ++j) {
    float4 tq = q4[j], tk = k4p[j];
    qv[4*j] = tq.x; qv[4*j+1] = tq.y; qv[4*j+2] = tq.z; qv[4*j+3] = tq.w;
    kv[4*j] = tk.x; kv[4*j+1] = tk.y; kv[4*j+2] = tk.z; kv[4*j+3] = tk.w;
  }
  #pragma unroll
  for (int d = 0; d < 16; ++d) {
    qv[d] = fmaxf(fmaf(qv[d], spr[d],    spr[16+d]), 0.f);
    kv[d] = fmaxf(fmaf(kv[d], spr[32+d], spr[48+d]), 0.f);
  }
  unsigned qhw[8], qlw[8], khw[8], klw[8];
  #pragma unroll
  for (int j = 0; j < 8; ++j) {
    unsigned u0 = __float_as_uint(qv[2*j]),   u1 = __float_as_uint(qv[2*j+1]);
    unsigned h0 = u0 & 0xFFFF0000u, h1 = u1 & 0xFFFF0000u;
    float l0 = qv[2*j] - __uint_as_float(h0);
    float l1 = qv[2*j+1] - __uint_as_float(h1);
    qhw[j] = (h0 >> 16) | h1;
    qlw[j] = (__float_as_uint(l0) >> 16) | (__float_as_uint(l1) & 0xFFFF0000u);
    u0 = __float_as_uint(kv[2*j]); u1 = __float_as_uint(kv[2*j+1]);
    h0 = u0 & 0xFFFF0000u; h1 = u1 & 0xFFFF0000u;
    l0 = kv[2*j] - __uint_as_float(h0);
    l1 = kv[2*j+1] - __uint_as_float(h1);
    khw[j] = (h0 >> 16) | h1;
    klw[j] = (__float_as_uint(l0) >> 16) | (__float_as_uint(l1) & 0xFFFF0000u);
  }
  qh[(size_t)p*2+0] = make_uint4(qhw[0], qhw[1], qhw[2], qhw[3]);
  qh[(size_t)p*2+1] = make_uint4(qhw[4], qhw[5], qhw[6], qhw[7]);
  ql[(size_t)p*2+0] = make_uint4(qlw[0], qlw[1], qlw[2], qlw[3]);
  ql[(size_t)p*2+1] = make_uint4(qlw[4], qlw[5], qlw[6], qlw[7]);
  kh[(size_t)p*2+0] = make_uint4(khw[0], khw[1], khw[2], khw[3]);
  kh[(size_t)p*2+1] = make_uint4(khw[4], khw[5], khw[6], khw[7]);
  kl[(size_t)p*2+0] = make_uint4(klw[0], klw[1], klw[2], klw[3]);
  kl[(size_t)p*2+1] = make_uint4(klw[4], klw[5], klw[6], klw[7]);
  float4 vv = ((const float4*)vpT)[p];
  vfh[0*32768 + p] = (_Float16)fmaxf(fmaf(vv.x, spr[64], spr[67]), 0.f);
  vfh[1*32768 + p] = (_Float16)fmaxf(fmaf(vv.y, spr[65], spr[68]), 0.f);
  vfh[2*32768 + p] = (_Float16)fmaxf(fmaf(vv.z, spr[66], spr[69]), 0.f);
  vfh[3*32768 + p] = (_Float16)1.0f;
}

// ---- k5max: pass 1 — hi-only per-row max, 32x32x16, unroll-2 + max3 --------
// C layout (m74/m101): col=lane&31 (q pt m), row=(reg&3)+8*(reg>>2)+4*(lane>>5).
// blk: cc = blk&3 (1024-col chunk), rc = (blk>>2)&31, b = blk>>7.
__global__ __launch_bounds__(256, 4) void k5max(
    const uint4* __restrict__ qh, const uint4* __restrict__ kh,
    float* __restrict__ pmax2) {
  int tx = threadIdx.x;
  int cc = blockIdx.x & 3;
  int rc = (blockIdx.x >> 2) & 31;
  int b  = blockIdx.x >> 7;
  int w = tx >> 6, lane = tx & 63;
  int cl = lane & 31, hl = lane >> 5;
  int n0 = rc*128 + w*32;
  size_t pbase = (size_t)b*4096;
  bf16x8 aK = *(const bf16x8*)&kh[(pbase + n0 + cl)*2 + hl];
  f32x16 zero16;
  #pragma unroll
  for (int r = 0; r < 16; ++r) zero16[r] = 0.f;
  f32x16 lm = zero16;
  const uint4* qptr = &qh[(pbase + (size_t)cc*1024 + cl)*2 + hl];
  #pragma unroll 2
  for (int ct = 0; ct < 16; ++ct) {
    bf16x8 bQ1 = *(const bf16x8*)qptr;
    bf16x8 bQ2 = *(const bf16x8*)(qptr + 64);
    qptr += 128;                     // 64 points x 2 uint4
    f32x16 c1 = __builtin_amdgcn_mfma_f32_32x32x16_bf16(aK, bQ1, zero16, 0, 0, 0);
    f32x16 c2 = __builtin_amdgcn_mfma_f32_32x32x16_bf16(aK, bQ2, zero16, 0, 0, 0);
    #pragma unroll
    for (int r = 0; r < 16; ++r)
      lm[r] = fmaxf(fmaxf(lm[r], c1[r]), c2[r]);   // -> v_max3_f32
  }
  #pragma unroll
  for (int off = 1; off <= 16; off <<= 1) {
    #pragma unroll
    for (int r = 0; r < 16; ++r) lm[r] = fmaxf(lm[r], __shfl_xor(lm[r], off));
  }
  if (cl == 0) {
    #pragma unroll
    for (int r = 0; r < 16; ++r)
      pmax2[(size_t)cc*32768 + pbase + n0 + (r & 3) + 8*(r >> 2) + 4*hl] = lm[r];
  }
}

// ---- k5pv: pass 2 — 4 row-tiles/wave, fixed-M, PV accumulates in MFMA C ----
// blk: cb = blk&7 (512-col chunk), rb = blk>>3: b = rb>>5, rc = rb&31.
// wave w: rows n0 = rc*128 + w*64, tiles at n0 + {0,16,32,48}.
#define K5_TILE(BKH, BKL, MR, ACC)                                             \
  {                                                                            \
    f32x4 c = __builtin_amdgcn_mfma_f32_16x16x32_bf16(aQ, BKH, zero4, 0, 0, 0);\
    c = __builtin_amdgcn_mfma_f32_16x16x32_bf16(aQ, BKL, c, 0, 0, 0);          \
    union { fp16x2 h2[2]; f16x4 v4; } pw;                                      \
    pw.h2[0] = __builtin_amdgcn_cvt_pkrtz(EXP2F(c[0] - MR), EXP2F(c[1] - MR)); \
    pw.h2[1] = __builtin_amdgcn_cvt_pkrtz(EXP2F(c[2] - MR), EXP2F(c[3] - MR)); \
    ACC = __builtin_amdgcn_mfma_f32_16x16x16f16(av, pw.v4, ACC, 0, 0, 0);      \
  }

__global__ __launch_bounds__(128, 4) void k5pv(
    const uint4* __restrict__ qh, const uint4* __restrict__ ql,
    const uint4* __restrict__ kh, const uint4* __restrict__ kl,
    const _Float16* __restrict__ vfh, const float* __restrict__ pmax2,
    float* __restrict__ pl, float* __restrict__ pa0,
    float* __restrict__ pa1, float* __restrict__ pa2) {
  int tx = threadIdx.x;
  int cb = blockIdx.x & 7;
  int rb = blockIdx.x >> 3;
  int b  = rb >> 5;
  int rc = rb & 31;
  int w = tx >> 6, lane = tx & 63;
  int nl = lane & 15, g = lane >> 4, g1 = g & 1;
  int n0 = rc*128 + w*64;
  size_t pbase = (size_t)b*4096;
  size_t kp0 = (pbase + n0 + nl)*2 + g1;
  bf16x8 bKh0 = *(const bf16x8*)&kh[kp0];
  bf16x8 bKl0 = *(const bf16x8*)&kl[kp0];
  bf16x8 bKh1 = *(const bf16x8*)&kh[kp0 + 32];
  bf16x8 bKl1 = *(const bf16x8*)&kl[kp0 + 32];
  bf16x8 bKh2 = *(const bf16x8*)&kh[kp0 + 64];
  bf16x8 bKl2 = *(const bf16x8*)&kl[kp0 + 64];
  bf16x8 bKh3 = *(const bf16x8*)&kh[kp0 + 96];
  bf16x8 bKl3 = *(const bf16x8*)&kl[kp0 + 96];
  size_t mi = pbase + n0 + nl;
  float M0, M1, M2, M3;
  {
    float a0 = fmaxf(pmax2[mi],      pmax2[32768 + mi]);
    float b0 = fmaxf(pmax2[2*32768 + mi], pmax2[3*32768 + mi]);
    M0 = fmaxf(a0, b0);
    a0 = fmaxf(pmax2[mi+16],      pmax2[32768 + mi+16]);
    b0 = fmaxf(pmax2[2*32768 + mi+16], pmax2[3*32768 + mi+16]);
    M1 = fmaxf(a0, b0);
    a0 = fmaxf(pmax2[mi+32],      pmax2[32768 + mi+32]);
    b0 = fmaxf(pmax2[2*32768 + mi+32], pmax2[3*32768 + mi+32]);
    M2 = fmaxf(a0, b0);
    a0 = fmaxf(pmax2[mi+48],      pmax2[32768 + mi+48]);
    b0 = fmaxf(pmax2[2*32768 + mi+48], pmax2[3*32768 + mi+48]);
    M3 = fmaxf(a0, b0);
  }
  f32x4 zero4 = {0.f, 0.f, 0.f, 0.f};
  f32x4 acc0 = zero4, acc1 = zero4, acc2 = zero4, acc3 = zero4;
  size_t cbase = pbase + (size_t)cb*512;
  const uint4* qptr = ((g < 2) ? qh : ql) + (cbase + nl)*2 + g1;
  const _Float16* vptr = vfh + (size_t)nl*32768 + cbase + g*4;
  bool vload = (nl < 4);
  f16x4 zeroh = {(_Float16)0.f, (_Float16)0.f, (_Float16)0.f, (_Float16)0.f};
  #pragma unroll 2
  for (int ct = 0; ct < 32; ++ct) {
    bf16x8 aQ = *(const bf16x8*)qptr;
    qptr += 32;                           // 16 points x 2 uint4
    f16x4 av = zeroh;
    if (vload) av = *(const f16x4*)vptr;
    vptr += 16;
    K5_TILE(bKh0, bKl0, M0, acc0)
    K5_TILE(bKh1, bKl1, M1, acc1)
    K5_TILE(bKh2, bKl2, M2, acc2)
    K5_TILE(bKh3, bKl3, M3, acc3)
  }
  if (lane < 16) {
    size_t base = (size_t)cb*32768 + pbase + n0 + lane;
    pl[base]      = acc0[3]; pa0[base]      = acc0[0]; pa1[base]      = acc0[1]; pa2[base]      = acc0[2];
    pl[base + 16] = acc1[3]; pa0[base + 16] = acc1[0]; pa1[base + 16] = acc1[1]; pa2[base + 16] = acc1[2];
    pl[base + 32] = acc2[3]; pa0[base + 32] = acc2[0]; pa1[base + 32] = acc2[1]; pa2[base + 32] = acc2[2];
    pl[base + 48] = acc3[3]; pa0[base + 48] = acc3[0]; pa1[base + 48] = acc3[1]; pa2[base + 48] = acc3[2];
  }
}

// ---- k6: pure-sum merge of 8 column chunks + epilogue ----------------------
__global__ __launch_bounds__(256) void k6_merge(
    const float* __restrict__ pl, const float* __restrict__ pa0,
    const float* __restrict__ pa1, const float* __restrict__ pa2,
    const float* __restrict__ x, const float* __restrict__ alpha,
    float* __restrict__ out) {
  int row = blockIdx.x*256 + threadIdx.x;   // 0..32767
  float L = 0.f, A0 = 0.f, A1 = 0.f, A2 = 0.f;
  #pragma unroll
  for (int cb = 0; cb < 8; ++cb) {
    size_t i = (size_t)cb*32768 + row;
    L += pl[i]; A0 += pa0[i]; A1 += pa1[i]; A2 += pa2[i];
  }
  int b = row >> 12, n = row & 4095;
  float inv = 1.f / L, al = alpha[0];
  out[(size_t)(b*3+0)*NN + n] = fmaf(al, A0*inv, x[(size_t)(b*3+0)*NN + n]);
  out[(size_t)(b*3+1)*NN + n] = fmaf(al, A1*inv, x[(size_t)(b*3+1)*NN + n]);
  out[(size_t)(b*3+2)*NN + n] = fmaf(al, A2*inv, x[(size_t)(b*3+2)*NN + n]);
}

extern "C" void kernel_launch(void* const* d_in, const int* in_sizes, int n_in,
                              void* d_out, int out_size, void* d_ws, size_t ws_size,
                              hipStream_t stream) {
  const float* x    = (const float*)d_in[0];
  const float* w1   = (const float*)d_in[1];
  const float* g1   = (const float*)d_in[2];
  const float* b1   = (const float*)d_in[3];
  const float* w2   = (const float*)d_in[4];
  const float* wq   = (const float*)d_in[5];
  const float* g2   = (const float*)d_in[6];
  const float* b2   = (const float*)d_in[7];
  const float* wk   = (const float*)d_in[8];
  const float* g3   = (const float*)d_in[9];
  const float* b3   = (const float*)d_in[10];
  const float* wv   = (const float*)d_in[11];
  const float* g4   = (const float*)d_in[12];
  const float* b4   = (const float*)d_in[13];
  const float* alpha= (const float*)d_in[14];
  float* out = (float*)d_out;
  float* ws  = (float*)d_ws;

  float* qpT = ws + OFF_QPT;
  float* kpT = ws + OFF_KPT;
  float* vpT = ws + OFF_VPT;
  float* wt2 = ws + OFF_WT2;
  float* xp  = ws + OFF_XP;
  float* bst = ws + OFF_BS;
  uint4* qhb = (uint4*)(ws + OFF_QH);
  uint4* qlb = (uint4*)(ws + OFF_QL);
  uint4* khb = (uint4*)(ws + OFF_KH);
  uint4* klb = (uint4*)(ws + OFF_KL);
  _Float16* vfh = (_Float16*)(ws + OFF_VFH);
  float* pls = ws + OFF_PL;
  float* pa0 = ws + OFF_PA0;
  float* pa1 = ws + OFF_PA1;
  float* pa2 = ws + OFF_PA2;
  float* pmx = ws + OFF_PMX;

  kA_mom_wcomb<<<129, 256, 0, stream>>>(x, xp, w2, wq, wk, wv, wt2);
  kB_qkv<<<256, 128, 0, stream>>>(x, xp, w1, g1, b1, wt2, qpT, kpT, vpT, bst);
  kC_prep<<<128, 256, 0, stream>>>(qpT, kpT, vpT, bst, g2, b2, g3, b3, g4, b4,
                                   qhb, qlb, khb, klb, vfh);
  k5max<<<1024, 256, 0, stream>>>(qhb, khb, pmx);
  k5pv<<<2048, 128, 0, stream>>>(qhb, qlb, khb, klb, vfh, pmx, pls, pa0, pa1, pa2);
  k6_merge<<<128, 256, 0, stream>>>(pls, pa0, pa1, pa2, x, alpha, out);
}

// Round 17
// 94.323 us; speedup vs baseline: 1.6511x; 1.0386x over previous
//
#include <hip/hip_runtime.h>

#define EPS 1e-5f
constexpr int NN = 4096;
constexpr float INV_CNT = 1.0f / (8.0f * 4096.0f);
constexpr float LOG2E = 1.44269504f;

typedef __attribute__((ext_vector_type(8))) short bf16x8;
typedef __attribute__((ext_vector_type(4))) float f32x4;
typedef __attribute__((ext_vector_type(16))) float f32x16;
typedef __attribute__((ext_vector_type(4))) _Float16 f16x4;
typedef __fp16 fp16x2 __attribute__((ext_vector_type(2)));

#if __has_builtin(__builtin_amdgcn_exp2f)
#define EXP2F(x) __builtin_amdgcn_exp2f(x)
#else
#define EXP2F(x) exp2f(x)
#endif

// workspace layout (float offsets)
constexpr size_t OFF_QPT = 0;        // 524288
constexpr size_t OFF_KPT = 524288;   // 524288
constexpr size_t OFF_VPT = 1048576;  // 131072
constexpr size_t OFF_WT2 = 1179648;  // 2304
constexpr size_t OFF_XP  = 1181952;  // 1152
constexpr size_t OFF_BS  = 1183104;  // 17920
constexpr size_t OFF_QH  = 1201024;  // 262144
constexpr size_t OFF_QL  = 1463168;  // 262144
constexpr size_t OFF_KH  = 1725312;  // 262144
constexpr size_t OFF_KL  = 1987456;  // 262144
constexpr size_t OFF_VFH = 2249600;  // 262144 (16 rows x 32768 fp16; rows 0-3 live)
constexpr size_t OFF_PL  = 2511744;  // 8*32768 = 262144
constexpr size_t OFF_PA0 = 2773888;  // 262144
constexpr size_t OFF_PA1 = 3036032;  // 262144
constexpr size_t OFF_PA2 = 3298176;  // 262144
constexpr size_t OFF_PMX = 3560320;  // 4*32768 = 131072; end 3691392 = 14.8 MB

// ---- kA: blocks 0-127: x moments; block 128: combined weights --------------
__global__ __launch_bounds__(256) void kA_mom_wcomb(
    const float* __restrict__ x, float* __restrict__ xpart,
    const float* __restrict__ w2, const float* __restrict__ wq,
    const float* __restrict__ wk, const float* __restrict__ wv,
    float* __restrict__ wt2) {
  __shared__ float w2s[8192];
  __shared__ float wr[4480];
  __shared__ float sred[36];
  int tx = threadIdx.x;
  if (blockIdx.x < 128) {
    int idx = blockIdx.x * 256 + tx;
    int b = idx >> 12, n = idx & 4095;
    float x0 = x[(size_t)(b*3+0)*NN + n];
    float x1 = x[(size_t)(b*3+1)*NN + n];
    float x2 = x[(size_t)(b*3+2)*NN + n];
    float m[9] = {x0, x1, x2, x0*x0, x0*x1, x0*x2, x1*x1, x1*x2, x2*x2};
    #pragma unroll
    for (int off = 32; off; off >>= 1) {
      #pragma unroll
      for (int j = 0; j < 9; ++j) m[j] += __shfl_xor(m[j], off);
    }
    int w = tx >> 6;
    if ((tx & 63) == 0) {
      #pragma unroll
      for (int j = 0; j < 9; ++j) sred[w*9+j] = m[j];
    }
    __syncthreads();
    if (tx < 9) xpart[tx*128 + blockIdx.x] = sred[tx] + sred[9+tx] + sred[18+tx] + sred[27+tx];
  } else {
    for (int i = tx; i < 8192; i += 256) w2s[i] = w2[i];
    for (int i = tx; i < 2048; i += 256) { wr[i] = wq[i]; wr[2048+i] = wk[i]; }
    for (int i = tx; i < 384; i += 256) wr[4096+i] = wv[i];
    __syncthreads();
    for (int e = tx; e < 2240; e += 256) {
      int j = e >> 6, c = e & 63;
      float s = 0.f;
      #pragma unroll 4
      for (int o = 0; o < 128; ++o) s = fmaf(wr[j*128+o], w2s[o*64+c], s);
      wt2[c*36 + j] = s;
    }
  }
}

// ---- kB: (f1 fused) per point -> qa/ka/va + block-partial stats ------------
__global__ __launch_bounds__(128) void kB_qkv(
    const float* __restrict__ x, const float* __restrict__ xpart,
    const float* __restrict__ w1, const float* __restrict__ g1,
    const float* __restrict__ b1, const float* __restrict__ wt2,
    float* __restrict__ qpT, float* __restrict__ kpT, float* __restrict__ vpT,
    float* __restrict__ bs) {
  __shared__ float4 w1s[64];
  __shared__ float4 wt2s[576];
  __shared__ float sred[140];
  __shared__ float mom[9];
  int tx = threadIdx.x;
  for (int i = tx; i < 576; i += 128) wt2s[i] = ((const float4*)wt2)[i];
  if (tx < 9) {
    float acc = 0.f;
    #pragma unroll 8
    for (int i = 0; i < 128; ++i) acc += xpart[tx*128 + i];
    mom[tx] = acc * INV_CNT;
  }
  __syncthreads();
  if (tx < 64) {
    int c = tx;
    float a = w1[c*3], b_ = w1[c*3+1], d = w1[c*3+2];
    float mean = a*mom[0] + b_*mom[1] + d*mom[2];
    float e2 = a*a*mom[3] + b_*b_*mom[6] + d*d*mom[8]
             + 2.f*(a*b_*mom[4] + a*d*mom[5] + b_*d*mom[7]);
    float sc = g1[c] * rsqrtf(e2 - mean*mean + EPS);
    w1s[c] = make_float4(a*sc, b_*sc, d*sc, fmaf(-mean, sc, b1[c]));
  }
  __syncthreads();
  int idx = blockIdx.x*128 + tx;
  int b = idx >> 12, n = idx & 4095;
  float x0 = x[(size_t)(b*3+0)*NN + n];
  float x1 = x[(size_t)(b*3+1)*NN + n];
  float x2 = x[(size_t)(b*3+2)*NN + n];
  float qa[16] = {}, ka[16] = {};
  float va0 = 0.f, va1 = 0.f, va2 = 0.f;
  #pragma unroll 4
  for (int c = 0; c < 64; ++c) {
    float4 w = w1s[c];
    float h = fmaf(w.x, x0, fmaf(w.y, x1, fmaf(w.z, x2, w.w)));
    h = h > 0.f ? h : 0.2f*h;
    #pragma unroll
    for (int j = 0; j < 4; ++j) {
      float4 A = wt2s[c*9 + j];
      qa[4*j+0] = fmaf(A.x, h, qa[4*j+0]);
      qa[4*j+1] = fmaf(A.y, h, qa[4*j+1]);
      qa[4*j+2] = fmaf(A.z, h, qa[4*j+2]);
      qa[4*j+3] = fmaf(A.w, h, qa[4*j+3]);
      float4 B = wt2s[c*9 + 4 + j];
      ka[4*j+0] = fmaf(B.x, h, ka[4*j+0]);
      ka[4*j+1] = fmaf(B.y, h, ka[4*j+1]);
      ka[4*j+2] = fmaf(B.z, h, ka[4*j+2]);
      ka[4*j+3] = fmaf(B.w, h, ka[4*j+3]);
    }
    float4 V = wt2s[c*9 + 8];
    va0 = fmaf(V.x, h, va0); va1 = fmaf(V.y, h, va1); va2 = fmaf(V.z, h, va2);
  }
  float4* qo = (float4*)(qpT + (size_t)idx*16);
  float4* ko = (float4*)(kpT + (size_t)idx*16);
  #pragma unroll
  for (int j = 0; j < 4; ++j) {
    qo[j] = make_float4(qa[4*j], qa[4*j+1], qa[4*j+2], qa[4*j+3]);
    ko[j] = make_float4(ka[4*j], ka[4*j+1], ka[4*j+2], ka[4*j+3]);
  }
  ((float4*)vpT)[idx] = make_float4(va0, va1, va2, 0.f);
  int w = tx >> 6;
  bool lead = ((tx & 63) == 0);
  #pragma unroll
  for (int d = 0; d < 16; ++d) {
    float s = qa[d], q = qa[d]*qa[d];
    #pragma unroll
    for (int off = 32; off; off >>= 1) { s += __shfl_xor(s, off); q += __shfl_xor(q, off); }
    if (lead) { sred[w*70 + d] = s; sred[w*70 + 16 + d] = q; }
    s = ka[d]; q = ka[d]*ka[d];
    #pragma unroll
    for (int off = 32; off; off >>= 1) { s += __shfl_xor(s, off); q += __shfl_xor(q, off); }
    if (lead) { sred[w*70 + 32 + d] = s; sred[w*70 + 48 + d] = q; }
  }
  float vv[3] = {va0, va1, va2};
  #pragma unroll
  for (int d = 0; d < 3; ++d) {
    float s = vv[d], q = vv[d]*vv[d];
    #pragma unroll
    for (int off = 32; off; off >>= 1) { s += __shfl_xor(s, off); q += __shfl_xor(q, off); }
    if (lead) { sred[w*70 + 64 + d] = s; sred[w*70 + 67 + d] = q; }
  }
  __syncthreads();
  if (tx < 70)
    bs[tx*256 + blockIdx.x] = sred[tx] + sred[70+tx];
}

// ---- kC: (f2 fused) BN+ReLU, q scaled by log2e, hi/lo split, v->fp16 -------
__global__ __launch_bounds__(256) void kC_prep(
    const float* __restrict__ qpT, const float* __restrict__ kpT,
    const float* __restrict__ vpT, const float* __restrict__ bs,
    const float* __restrict__ g2, const float* __restrict__ b2,
    const float* __restrict__ g3, const float* __restrict__ b3,
    const float* __restrict__ g4, const float* __restrict__ b4,
    uint4* __restrict__ qh, uint4* __restrict__ ql,
    uint4* __restrict__ kh, uint4* __restrict__ kl,
    _Float16* __restrict__ vfh) {
  __shared__ float tot[70];
  __shared__ float spr[70];
  int tx = threadIdx.x;
  if (tx < 70) {
    float acc = 0.f;
    #pragma unroll 8
    for (int i = 0; i < 256; ++i) acc += bs[tx*256 + i];
    tot[tx] = acc * INV_CNT;
  }
  __syncthreads();
  if (tx < 16) {
    float mean = tot[tx], var = tot[16+tx] - mean*mean;
    float sc = g2[tx]*rsqrtf(var + EPS);
    spr[tx] = sc * LOG2E;
    spr[16+tx] = fmaf(-mean, sc, b2[tx]) * LOG2E;
  } else if (tx < 32) {
    int d = tx-16;
    float mean = tot[32+d], var = tot[48+d] - mean*mean;
    float sc = g3[d]*rsqrtf(var + EPS);
    spr[32+d] = sc; spr[48+d] = fmaf(-mean, sc, b3[d]);
  } else if (tx < 35) {
    int d = tx-32;
    float mean = tot[64+d], var = tot[67+d] - mean*mean;
    float sc = g4[d]*rsqrtf(var + EPS);
    spr[64+d] = sc; spr[67+d] = fmaf(-mean, sc, b4[d]);
  }
  __syncthreads();
  int p = blockIdx.x*256 + tx;
  float qv[16], kv[16];
  const float4* q4 = (const float4*)(qpT + (size_t)p*16);
  const float4* k4p = (const float4*)(kpT + (size_t)p*16);
  #pragma unroll
  for (int j = 0; j < 4; ++j) {
    float4 tq = q4[j], tk = k4p[j];
    qv[4*j] = tq.x; qv[4*j+1] = tq.y; qv[4*j+2] = tq.z; qv[4*j+3] = tq.w;
    kv[4*j] = tk.x; kv[4*j+1] = tk.y; kv[4*j+2] = tk.z; kv[4*j+3] = tk.w;
  }
  #pragma unroll
  for (int d = 0; d < 16; ++d) {
    qv[d] = fmaxf(fmaf(qv[d], spr[d],    spr[16+d]), 0.f);
    kv[d] = fmaxf(fmaf(kv[d], spr[32+d], spr[48+d]), 0.f);
  }
  unsigned qhw[8], qlw[8], khw[8], klw[8];
  #pragma unroll
  for (int j = 0; j < 8; ++j) {
    unsigned u0 = __float_as_uint(qv[2*j]),   u1 = __float_as_uint(qv[2*j+1]);
    unsigned h0 = u0 & 0xFFFF0000u, h1 = u1 & 0xFFFF0000u;
    float l0 = qv[2*j] - __uint_as_float(h0);
    float l1 = qv[2*j+1] - __uint_as_float(h1);
    qhw[j] = (h0 >> 16) | h1;
    qlw[j] = (__float_as_uint(l0) >> 16) | (__float_as_uint(l1) & 0xFFFF0000u);
    u0 = __float_as_uint(kv[2*j]); u1 = __float_as_uint(kv[2*j+1]);
    h0 = u0 & 0xFFFF0000u; h1 = u1 & 0xFFFF0000u;
    l0 = kv[2*j] - __uint_as_float(h0);
    l1 = kv[2*j+1] - __uint_as_float(h1);
    khw[j] = (h0 >> 16) | h1;
    klw[j] = (__float_as_uint(l0) >> 16) | (__float_as_uint(l1) & 0xFFFF0000u);
  }
  qh[(size_t)p*2+0] = make_uint4(qhw[0], qhw[1], qhw[2], qhw[3]);
  qh[(size_t)p*2+1] = make_uint4(qhw[4], qhw[5], qhw[6], qhw[7]);
  ql[(size_t)p*2+0] = make_uint4(qlw[0], qlw[1], qlw[2], qlw[3]);
  ql[(size_t)p*2+1] = make_uint4(qlw[4], qlw[5], qlw[6], qlw[7]);
  kh[(size_t)p*2+0] = make_uint4(khw[0], khw[1], khw[2], khw[3]);
  kh[(size_t)p*2+1] = make_uint4(khw[4], khw[5], khw[6], khw[7]);
  kl[(size_t)p*2+0] = make_uint4(klw[0], klw[1], klw[2], klw[3]);
  kl[(size_t)p*2+1] = make_uint4(klw[4], klw[5], klw[6], klw[7]);
  float4 vv = ((const float4*)vpT)[p];
  vfh[0*32768 + p] = (_Float16)fmaxf(fmaf(vv.x, spr[64], spr[67]), 0.f);
  vfh[1*32768 + p] = (_Float16)fmaxf(fmaf(vv.y, spr[65], spr[68]), 0.f);
  vfh[2*32768 + p] = (_Float16)fmaxf(fmaf(vv.z, spr[66], spr[69]), 0.f);
  vfh[3*32768 + p] = (_Float16)1.0f;
}

// ---- k5max: pass 1 — hi-only per-row max, 32x32x16, prefetch + max3 --------
// C layout (m74/m101): col=lane&31, row=(reg&3)+8*(reg>>2)+4*(lane>>5).
// blk: cc = blk&3 (1024-col chunk), rc = (blk>>2)&31, b = blk>>7.
__global__ __launch_bounds__(256, 4) void k5max(
    const uint4* __restrict__ qh, const uint4* __restrict__ kh,
    float* __restrict__ pmax2) {
  int tx = threadIdx.x;
  int cc = blockIdx.x & 3;
  int rc = (blockIdx.x >> 2) & 31;
  int b  = blockIdx.x >> 7;
  int w = tx >> 6, lane = tx & 63;
  int cl = lane & 31, hl = lane >> 5;
  int n0 = rc*128 + w*32;
  size_t pbase = (size_t)b*4096;
  bf16x8 aK = *(const bf16x8*)&kh[(pbase + n0 + cl)*2 + hl];
  f32x16 zero16;
  #pragma unroll
  for (int r = 0; r < 16; ++r) zero16[r] = 0.f;
  f32x16 lm = zero16;
  const uint4* qptr = &qh[(pbase + (size_t)cc*1024 + cl)*2 + hl];
  bf16x8 bQ1 = *(const bf16x8*)qptr;
  bf16x8 bQ2 = *(const bf16x8*)(qptr + 64);
  #pragma unroll 2
  for (int ct = 0; ct < 16; ++ct) {
    bf16x8 q1 = bQ1, q2 = bQ2;
    qptr += 128;                     // 64 points x 2 uint4
    if (ct < 15) {                   // prefetch next pair under the MFMAs
      bQ1 = *(const bf16x8*)qptr;
      bQ2 = *(const bf16x8*)(qptr + 64);
    }
    f32x16 c1 = __builtin_amdgcn_mfma_f32_32x32x16_bf16(aK, q1, zero16, 0, 0, 0);
    f32x16 c2 = __builtin_amdgcn_mfma_f32_32x32x16_bf16(aK, q2, zero16, 0, 0, 0);
    #pragma unroll
    for (int r = 0; r < 16; ++r)
      lm[r] = fmaxf(fmaxf(lm[r], c1[r]), c2[r]);   // -> v_max3_f32
  }
  #pragma unroll
  for (int off = 1; off <= 16; off <<= 1) {
    #pragma unroll
    for (int r = 0; r < 16; ++r) lm[r] = fmaxf(lm[r], __shfl_xor(lm[r], off));
  }
  if (cl == 0) {
    #pragma unroll
    for (int r = 0; r < 16; ++r)
      pmax2[(size_t)cc*32768 + pbase + n0 + (r & 3) + 8*(r >> 2) + 4*hl] = lm[r];
  }
}

// ---- k5pv: pass 2 — 4 row-tiles/wave, fixed-M, MFMA-C accum, prefetch ------
// blk: cb = blk&7 (512-col chunk), rb = blk>>3: b = rb>>5, rc = rb&31.
// wave w: rows n0 = rc*128 + w*64, tiles at n0 + {0,16,32,48}.
#define K5_TILE(BKH, BKL, MR, ACC)                                             \
  {                                                                            \
    f32x4 c = __builtin_amdgcn_mfma_f32_16x16x32_bf16(aQ, BKH, zero4, 0, 0, 0);\
    c = __builtin_amdgcn_mfma_f32_16x16x32_bf16(aQ, BKL, c, 0, 0, 0);          \
    union { fp16x2 h2[2]; f16x4 v4; } pw;                                      \
    pw.h2[0] = __builtin_amdgcn_cvt_pkrtz(EXP2F(c[0] - MR), EXP2F(c[1] - MR)); \
    pw.h2[1] = __builtin_amdgcn_cvt_pkrtz(EXP2F(c[2] - MR), EXP2F(c[3] - MR)); \
    ACC = __builtin_amdgcn_mfma_f32_16x16x16f16(av, pw.v4, ACC, 0, 0, 0);      \
  }

__global__ __launch_bounds__(128, 5) void k5pv(
    const uint4* __restrict__ qh, const uint4* __restrict__ ql,
    const uint4* __restrict__ kh, const uint4* __restrict__ kl,
    const _Float16* __restrict__ vfh, const float* __restrict__ pmax2,
    float* __restrict__ pl, float* __restrict__ pa0,
    float* __restrict__ pa1, float* __restrict__ pa2) {
  int tx = threadIdx.x;
  int cb = blockIdx.x & 7;
  int rb = blockIdx.x >> 3;
  int b  = rb >> 5;
  int rc = rb & 31;
  int w = tx >> 6, lane = tx & 63;
  int nl = lane & 15, g = lane >> 4, g1 = g & 1;
  int n0 = rc*128 + w*64;
  size_t pbase = (size_t)b*4096;
  size_t kp0 = (pbase + n0 + nl)*2 + g1;
  bf16x8 bKh0 = *(const bf16x8*)&kh[kp0];
  bf16x8 bKl0 = *(const bf16x8*)&kl[kp0];
  bf16x8 bKh1 = *(const bf16x8*)&kh[kp0 + 32];
  bf16x8 bKl1 = *(const bf16x8*)&kl[kp0 + 32];
  bf16x8 bKh2 = *(const bf16x8*)&kh[kp0 + 64];
  bf16x8 bKl2 = *(const bf16x8*)&kl[kp0 + 64];
  bf16x8 bKh3 = *(const bf16x8*)&kh[kp0 + 96];
  bf16x8 bKl3 = *(const bf16x8*)&kl[kp0 + 96];
  size_t mi = pbase + n0 + nl;
  float M0, M1, M2, M3;
  {
    float a0 = fmaxf(pmax2[mi],      pmax2[32768 + mi]);
    float b0 = fmaxf(pmax2[2*32768 + mi], pmax2[3*32768 + mi]);
    M0 = fmaxf(a0, b0);
    a0 = fmaxf(pmax2[mi+16],      pmax2[32768 + mi+16]);
    b0 = fmaxf(pmax2[2*32768 + mi+16], pmax2[3*32768 + mi+16]);
    M1 = fmaxf(a0, b0);
    a0 = fmaxf(pmax2[mi+32],      pmax2[32768 + mi+32]);
    b0 = fmaxf(pmax2[2*32768 + mi+32], pmax2[3*32768 + mi+32]);
    M2 = fmaxf(a0, b0);
    a0 = fmaxf(pmax2[mi+48],      pmax2[32768 + mi+48]);
    b0 = fmaxf(pmax2[2*32768 + mi+48], pmax2[3*32768 + mi+48]);
    M3 = fmaxf(a0, b0);
  }
  f32x4 zero4 = {0.f, 0.f, 0.f, 0.f};
  f32x4 acc0 = zero4, acc1 = zero4, acc2 = zero4, acc3 = zero4;
  size_t cbase = pbase + (size_t)cb*512;
  const uint4* qptr = ((g < 2) ? qh : ql) + (cbase + nl)*2 + g1;
  const _Float16* vptr = vfh + (size_t)nl*32768 + cbase + g*4;
  bool vload = (nl < 4);
  f16x4 zeroh = {(_Float16)0.f, (_Float16)0.f, (_Float16)0.f, (_Float16)0.f};
  // prefetch iteration 0
  bf16x8 aQn = *(const bf16x8*)qptr;
  f16x4 avn = zeroh;
  if (vload) avn = *(const f16x4*)vptr;
  #pragma unroll 2
  for (int ct = 0; ct < 32; ++ct) {
    bf16x8 aQ = aQn;
    f16x4 av = avn;
    qptr += 32;                           // 16 points x 2 uint4
    vptr += 16;
    if (ct < 31) {                        // prefetch ct+1 under the MFMAs
      aQn = *(const bf16x8*)qptr;
      if (vload) avn = *(const f16x4*)vptr;
    }
    K5_TILE(bKh0, bKl0, M0, acc0)
    K5_TILE(bKh1, bKl1, M1, acc1)
    K5_TILE(bKh2, bKl2, M2, acc2)
    K5_TILE(bKh3, bKl3, M3, acc3)
  }
  if (lane < 16) {
    size_t base = (size_t)cb*32768 + pbase + n0 + lane;
    pl[base]      = acc0[3]; pa0[base]      = acc0[0]; pa1[base]      = acc0[1]; pa2[base]      = acc0[2];
    pl[base + 16] = acc1[3]; pa0[base + 16] = acc1[0]; pa1[base + 16] = acc1[1]; pa2[base + 16] = acc1[2];
    pl[base + 32] = acc2[3]; pa0[base + 32] = acc2[0]; pa1[base + 32] = acc2[1]; pa2[base + 32] = acc2[2];
    pl[base + 48] = acc3[3]; pa0[base + 48] = acc3[0]; pa1[base + 48] = acc3[1]; pa2[base + 48] = acc3[2];
  }
}

// ---- k6: pure-sum merge of 8 column chunks + epilogue ----------------------
__global__ __launch_bounds__(256) void k6_merge(
    const float* __restrict__ pl, const float* __restrict__ pa0,
    const float* __restrict__ pa1, const float* __restrict__ pa2,
    const float* __restrict__ x, const float* __restrict__ alpha,
    float* __restrict__ out) {
  int row = blockIdx.x*256 + threadIdx.x;   // 0..32767
  float L = 0.f, A0 = 0.f, A1 = 0.f, A2 = 0.f;
  #pragma unroll
  for (int cb = 0; cb < 8; ++cb) {
    size_t i = (size_t)cb*32768 + row;
    L += pl[i]; A0 += pa0[i]; A1 += pa1[i]; A2 += pa2[i];
  }
  int b = row >> 12, n = row & 4095;
  float inv = 1.f / L, al = alpha[0];
  out[(size_t)(b*3+0)*NN + n] = fmaf(al, A0*inv, x[(size_t)(b*3+0)*NN + n]);
  out[(size_t)(b*3+1)*NN + n] = fmaf(al, A1*inv, x[(size_t)(b*3+1)*NN + n]);
  out[(size_t)(b*3+2)*NN + n] = fmaf(al, A2*inv, x[(size_t)(b*3+2)*NN + n]);
}

extern "C" void kernel_launch(void* const* d_in, const int* in_sizes, int n_in,
                              void* d_out, int out_size, void* d_ws, size_t ws_size,
                              hipStream_t stream) {
  const float* x    = (const float*)d_in[0];
  const float* w1   = (const float*)d_in[1];
  const float* g1   = (const float*)d_in[2];
  const float* b1   = (const float*)d_in[3];
  const float* w2   = (const float*)d_in[4];
  const float* wq   = (const float*)d_in[5];
  const float* g2   = (const float*)d_in[6];
  const float* b2   = (const float*)d_in[7];
  const float* wk   = (const float*)d_in[8];
  const float* g3   = (const float*)d_in[9];
  const float* b3   = (const float*)d_in[10];
  const float* wv   = (const float*)d_in[11];
  const float* g4   = (const float*)d_in[12];
  const float* b4   = (const float*)d_in[13];
  const float* alpha= (const float*)d_in[14];
  float* out = (float*)d_out;
  float* ws  = (float*)d_ws;

  float* qpT = ws + OFF_QPT;
  float* kpT = ws + OFF_KPT;
  float* vpT = ws + OFF_VPT;
  float* wt2 = ws + OFF_WT2;
  float* xp  = ws + OFF_XP;
  float* bst = ws + OFF_BS;
  uint4* qhb = (uint4*)(ws + OFF_QH);
  uint4* qlb = (uint4*)(ws + OFF_QL);
  uint4* khb = (uint4*)(ws + OFF_KH);
  uint4* klb = (uint4*)(ws + OFF_KL);
  _Float16* vfh = (_Float16*)(ws + OFF_VFH);
  float* pls = ws + OFF_PL;
  float* pa0 = ws + OFF_PA0;
  float* pa1 = ws + OFF_PA1;
  float* pa2 = ws + OFF_PA2;
  float* pmx = ws + OFF_PMX;

  kA_mom_wcomb<<<129, 256, 0, stream>>>(x, xp, w2, wq, wk, wv, wt2);
  kB_qkv<<<256, 128, 0, stream>>>(x, xp, w1, g1, b1, wt2, qpT, kpT, vpT, bst);
  kC_prep<<<128, 256, 0, stream>>>(qpT, kpT, vpT, bst, g2, b2, g3, b3, g4, b4,
                                   qhb, qlb, khb, klb, vfh);
  k5max<<<1024, 256, 0, stream>>>(qhb, khb, pmx);
  k5pv<<<2048, 128, 0, stream>>>(qhb, qlb, khb, klb, vfh, pmx, pls, pa0, pa1, pa2);
  k6_merge<<<128, 256, 0, stream>>>(pls, pa0, pa1, pa2, x, alpha, out);
}

// Round 19
// 93.425 us; speedup vs baseline: 1.6670x; 1.0096x over previous
//
#include <hip/hip_runtime.h>

#define EPS 1e-5f
constexpr int NN = 4096;
constexpr float INV_CNT = 1.0f / (8.0f * 4096.0f);
constexpr float LOG2E = 1.44269504f;

typedef __attribute__((ext_vector_type(8))) short bf16x8;
typedef __attribute__((ext_vector_type(4))) float f32x4;
typedef __attribute__((ext_vector_type(4))) _Float16 f16x4;
typedef __fp16 fp16x2 __attribute__((ext_vector_type(2)));

#if __has_builtin(__builtin_amdgcn_exp2f)
#define EXP2F(x) __builtin_amdgcn_exp2f(x)
#else
#define EXP2F(x) exp2f(x)
#endif

// workspace layout (float offsets)
constexpr size_t OFF_QPT = 0;        // 524288
constexpr size_t OFF_KPT = 524288;   // 524288
constexpr size_t OFF_VPT = 1048576;  // 131072
constexpr size_t OFF_WT2 = 1179648;  // 2304
constexpr size_t OFF_XP  = 1181952;  // 1152
constexpr size_t OFF_BS  = 1183104;  // 17920
constexpr size_t OFF_QH  = 1201024;  // 262144
constexpr size_t OFF_QL  = 1463168;  // 262144
constexpr size_t OFF_KH  = 1725312;  // 262144
constexpr size_t OFF_KL  = 1987456;  // 262144
constexpr size_t OFF_VFH = 2249600;  // 262144 (16 rows x 32768 fp16; rows 0-3 live)
constexpr size_t OFF_PL  = 2511744;  // 8*32768 = 262144
constexpr size_t OFF_PA0 = 2773888;  // 262144
constexpr size_t OFF_PA1 = 3036032;  // 262144
constexpr size_t OFF_PA2 = 3298176;  // 262144
constexpr size_t OFF_PM  = 3560320;  // 8*32768 = 262144; end 3822464 = 15.3 MB

// ---- kA: blocks 0-127: x moments; block 128: combined weights --------------
__global__ __launch_bounds__(256) void kA_mom_wcomb(
    const float* __restrict__ x, float* __restrict__ xpart,
    const float* __restrict__ w2, const float* __restrict__ wq,
    const float* __restrict__ wk, const float* __restrict__ wv,
    float* __restrict__ wt2) {
  __shared__ float w2s[8192];
  __shared__ float wr[4480];
  __shared__ float sred[36];
  int tx = threadIdx.x;
  if (blockIdx.x < 128) {
    int idx = blockIdx.x * 256 + tx;
    int b = idx >> 12, n = idx & 4095;
    float x0 = x[(size_t)(b*3+0)*NN + n];
    float x1 = x[(size_t)(b*3+1)*NN + n];
    float x2 = x[(size_t)(b*3+2)*NN + n];
    float m[9] = {x0, x1, x2, x0*x0, x0*x1, x0*x2, x1*x1, x1*x2, x2*x2};
    #pragma unroll
    for (int off = 32; off; off >>= 1) {
      #pragma unroll
      for (int j = 0; j < 9; ++j) m[j] += __shfl_xor(m[j], off);
    }
    int w = tx >> 6;
    if ((tx & 63) == 0) {
      #pragma unroll
      for (int j = 0; j < 9; ++j) sred[w*9+j] = m[j];
    }
    __syncthreads();
    if (tx < 9) xpart[tx*128 + blockIdx.x] = sred[tx] + sred[9+tx] + sred[18+tx] + sred[27+tx];
  } else {
    for (int i = tx; i < 8192; i += 256) w2s[i] = w2[i];
    for (int i = tx; i < 2048; i += 256) { wr[i] = wq[i]; wr[2048+i] = wk[i]; }
    for (int i = tx; i < 384; i += 256) wr[4096+i] = wv[i];
    __syncthreads();
    for (int e = tx; e < 2240; e += 256) {
      int j = e >> 6, c = e & 63;
      float s = 0.f;
      #pragma unroll 4
      for (int o = 0; o < 128; ++o) s = fmaf(wr[j*128+o], w2s[o*64+c], s);
      wt2[c*36 + j] = s;
    }
  }
}

// ---- kB: (f1 fused) per point -> qa/ka/va + block-partial stats ------------
__global__ __launch_bounds__(128) void kB_qkv(
    const float* __restrict__ x, const float* __restrict__ xpart,
    const float* __restrict__ w1, const float* __restrict__ g1,
    const float* __restrict__ b1, const float* __restrict__ wt2,
    float* __restrict__ qpT, float* __restrict__ kpT, float* __restrict__ vpT,
    float* __restrict__ bs) {
  __shared__ float4 w1s[64];
  __shared__ float4 wt2s[576];
  __shared__ float sred[140];
  __shared__ float mom[9];
  int tx = threadIdx.x;
  for (int i = tx; i < 576; i += 128) wt2s[i] = ((const float4*)wt2)[i];
  if (tx < 9) {
    float acc = 0.f;
    #pragma unroll 8
    for (int i = 0; i < 128; ++i) acc += xpart[tx*128 + i];
    mom[tx] = acc * INV_CNT;
  }
  __syncthreads();
  if (tx < 64) {
    int c = tx;
    float a = w1[c*3], b_ = w1[c*3+1], d = w1[c*3+2];
    float mean = a*mom[0] + b_*mom[1] + d*mom[2];
    float e2 = a*a*mom[3] + b_*b_*mom[6] + d*d*mom[8]
             + 2.f*(a*b_*mom[4] + a*d*mom[5] + b_*d*mom[7]);
    float sc = g1[c] * rsqrtf(e2 - mean*mean + EPS);
    w1s[c] = make_float4(a*sc, b_*sc, d*sc, fmaf(-mean, sc, b1[c]));
  }
  __syncthreads();
  int idx = blockIdx.x*128 + tx;
  int b = idx >> 12, n = idx & 4095;
  float x0 = x[(size_t)(b*3+0)*NN + n];
  float x1 = x[(size_t)(b*3+1)*NN + n];
  float x2 = x[(size_t)(b*3+2)*NN + n];
  float qa[16] = {}, ka[16] = {};
  float va0 = 0.f, va1 = 0.f, va2 = 0.f;
  #pragma unroll 4
  for (int c = 0; c < 64; ++c) {
    float4 w = w1s[c];
    float h = fmaf(w.x, x0, fmaf(w.y, x1, fmaf(w.z, x2, w.w)));
    h = h > 0.f ? h : 0.2f*h;
    #pragma unroll
    for (int j = 0; j < 4; ++j) {
      float4 A = wt2s[c*9 + j];
      qa[4*j+0] = fmaf(A.x, h, qa[4*j+0]);
      qa[4*j+1] = fmaf(A.y, h, qa[4*j+1]);
      qa[4*j+2] = fmaf(A.z, h, qa[4*j+2]);
      qa[4*j+3] = fmaf(A.w, h, qa[4*j+3]);
      float4 B = wt2s[c*9 + 4 + j];
      ka[4*j+0] = fmaf(B.x, h, ka[4*j+0]);
      ka[4*j+1] = fmaf(B.y, h, ka[4*j+1]);
      ka[4*j+2] = fmaf(B.z, h, ka[4*j+2]);
      ka[4*j+3] = fmaf(B.w, h, ka[4*j+3]);
    }
    float4 V = wt2s[c*9 + 8];
    va0 = fmaf(V.x, h, va0); va1 = fmaf(V.y, h, va1); va2 = fmaf(V.z, h, va2);
  }
  float4* qo = (float4*)(qpT + (size_t)idx*16);
  float4* ko = (float4*)(kpT + (size_t)idx*16);
  #pragma unroll
  for (int j = 0; j < 4; ++j) {
    qo[j] = make_float4(qa[4*j], qa[4*j+1], qa[4*j+2], qa[4*j+3]);
    ko[j] = make_float4(ka[4*j], ka[4*j+1], ka[4*j+2], ka[4*j+3]);
  }
  ((float4*)vpT)[idx] = make_float4(va0, va1, va2, 0.f);
  int w = tx >> 6;
  bool lead = ((tx & 63) == 0);
  #pragma unroll
  for (int d = 0; d < 16; ++d) {
    float s = qa[d], q = qa[d]*qa[d];
    #pragma unroll
    for (int off = 32; off; off >>= 1) { s += __shfl_xor(s, off); q += __shfl_xor(q, off); }
    if (lead) { sred[w*70 + d] = s; sred[w*70 + 16 + d] = q; }
    s = ka[d]; q = ka[d]*ka[d];
    #pragma unroll
    for (int off = 32; off; off >>= 1) { s += __shfl_xor(s, off); q += __shfl_xor(q, off); }
    if (lead) { sred[w*70 + 32 + d] = s; sred[w*70 + 48 + d] = q; }
  }
  float vv[3] = {va0, va1, va2};
  #pragma unroll
  for (int d = 0; d < 3; ++d) {
    float s = vv[d], q = vv[d]*vv[d];
    #pragma unroll
    for (int off = 32; off; off >>= 1) { s += __shfl_xor(s, off); q += __shfl_xor(q, off); }
    if (lead) { sred[w*70 + 64 + d] = s; sred[w*70 + 67 + d] = q; }
  }
  __syncthreads();
  if (tx < 70)
    bs[tx*256 + blockIdx.x] = sred[tx] + sred[70+tx];
}

// ---- kC: (f2 fused) BN+ReLU, q scaled by log2e, hi/lo split, v->fp16 -------
__global__ __launch_bounds__(256) void kC_prep(
    const float* __restrict__ qpT, const float* __restrict__ kpT,
    const float* __restrict__ vpT, const float* __restrict__ bs,
    const float* __restrict__ g2, const float* __restrict__ b2,
    const float* __restrict__ g3, const float* __restrict__ b3,
    const float* __restrict__ g4, const float* __restrict__ b4,
    uint4* __restrict__ qh, uint4* __restrict__ ql,
    uint4* __restrict__ kh, uint4* __restrict__ kl,
    _Float16* __restrict__ vfh) {
  __shared__ float tot[70];
  __shared__ float spr[70];
  int tx = threadIdx.x;
  if (tx < 70) {
    float acc = 0.f;
    #pragma unroll 8
    for (int i = 0; i < 256; ++i) acc += bs[tx*256 + i];
    tot[tx] = acc * INV_CNT;
  }
  __syncthreads();
  if (tx < 16) {
    float mean = tot[tx], var = tot[16+tx] - mean*mean;
    float sc = g2[tx]*rsqrtf(var + EPS);
    spr[tx] = sc * LOG2E;
    spr[16+tx] = fmaf(-mean, sc, b2[tx]) * LOG2E;
  } else if (tx < 32) {
    int d = tx-16;
    float mean = tot[32+d], var = tot[48+d] - mean*mean;
    float sc = g3[d]*rsqrtf(var + EPS);
    spr[32+d] = sc; spr[48+d] = fmaf(-mean, sc, b3[d]);
  } else if (tx < 35) {
    int d = tx-32;
    float mean = tot[64+d], var = tot[67+d] - mean*mean;
    float sc = g4[d]*rsqrtf(var + EPS);
    spr[64+d] = sc; spr[67+d] = fmaf(-mean, sc, b4[d]);
  }
  __syncthreads();
  int p = blockIdx.x*256 + tx;
  float qv[16], kv[16];
  const float4* q4 = (const float4*)(qpT + (size_t)p*16);
  const float4* k4p = (const float4*)(kpT + (size_t)p*16);
  #pragma unroll
  for (int j = 0; j < 4; ++j) {
    float4 tq = q4[j], tk = k4p[j];
    qv[4*j] = tq.x; qv[4*j+1] = tq.y; qv[4*j+2] = tq.z; qv[4*j+3] = tq.w;
    kv[4*j] = tk.x; kv[4*j+1] = tk.y; kv[4*j+2] = tk.z; kv[4*j+3] = tk.w;
  }
  #pragma unroll
  for (int d = 0; d < 16; ++d) {
    qv[d] = fmaxf(fmaf(qv[d], spr[d],    spr[16+d]), 0.f);
    kv[d] = fmaxf(fmaf(kv[d], spr[32+d], spr[48+d]), 0.f);
  }
  unsigned qhw[8], qlw[8], khw[8], klw[8];
  #pragma unroll
  for (int j = 0; j < 8; ++j) {
    unsigned u0 = __float_as_uint(qv[2*j]),   u1 = __float_as_uint(qv[2*j+1]);
    unsigned h0 = u0 & 0xFFFF0000u, h1 = u1 & 0xFFFF0000u;
    float l0 = qv[2*j] - __uint_as_float(h0);
    float l1 = qv[2*j+1] - __uint_as_float(h1);
    qhw[j] = (h0 >> 16) | h1;
    qlw[j] = (__float_as_uint(l0) >> 16) | (__float_as_uint(l1) & 0xFFFF0000u);
    u0 = __float_as_uint(kv[2*j]); u1 = __float_as_uint(kv[2*j+1]);
    h0 = u0 & 0xFFFF0000u; h1 = u1 & 0xFFFF0000u;
    l0 = kv[2*j] - __uint_as_float(h0);
    l1 = kv[2*j+1] - __uint_as_float(h1);
    khw[j] = (h0 >> 16) | h1;
    klw[j] = (__float_as_uint(l0) >> 16) | (__float_as_uint(l1) & 0xFFFF0000u);
  }
  qh[(size_t)p*2+0] = make_uint4(qhw[0], qhw[1], qhw[2], qhw[3]);
  qh[(size_t)p*2+1] = make_uint4(qhw[4], qhw[5], qhw[6], qhw[7]);
  ql[(size_t)p*2+0] = make_uint4(qlw[0], qlw[1], qlw[2], qlw[3]);
  ql[(size_t)p*2+1] = make_uint4(qlw[4], qlw[5], qlw[6], qlw[7]);
  kh[(size_t)p*2+0] = make_uint4(khw[0], khw[1], khw[2], khw[3]);
  kh[(size_t)p*2+1] = make_uint4(khw[4], khw[5], khw[6], khw[7]);
  kl[(size_t)p*2+0] = make_uint4(klw[0], klw[1], klw[2], klw[3]);
  kl[(size_t)p*2+1] = make_uint4(klw[4], klw[5], klw[6], klw[7]);
  float4 vv = ((const float4*)vpT)[p];
  vfh[0*32768 + p] = (_Float16)fmaxf(fmaf(vv.x, spr[64], spr[67]), 0.f);
  vfh[1*32768 + p] = (_Float16)fmaxf(fmaf(vv.y, spr[65], spr[68]), 0.f);
  vfh[2*32768 + p] = (_Float16)fmaxf(fmaf(vv.z, spr[66], spr[69]), 0.f);
  vfh[3*32768 + p] = (_Float16)1.0f;
}

// ---- k5pv: fused chunk-local max pre-pass + fixed-M PV loop ----------------
// Pre-pass M_chunk[r] = max over this 512-col chunk of (qh+ql)·kh — a lower
// bound of the full score with gap <= (qh+ql)·kl ~ 0.78 log2 => pw <= 1.72,
// fp16-safe; softmax exact after k6's max-merge (R10-verified pattern).
// blk: cb = blk&7 (512-col chunk), rb = blk>>3: b = rb>>5, rc = rb&31.
#define K5_TILE(BKH, BKL, MR, ACC)                                             \
  {                                                                            \
    f32x4 c = __builtin_amdgcn_mfma_f32_16x16x32_bf16(aQ, BKH, zero4, 0, 0, 0);\
    c = __builtin_amdgcn_mfma_f32_16x16x32_bf16(aQ, BKL, c, 0, 0, 0);          \
    union { fp16x2 h2[2]; f16x4 v4; } pw;                                      \
    pw.h2[0] = __builtin_amdgcn_cvt_pkrtz(EXP2F(c[0] - MR), EXP2F(c[1] - MR)); \
    pw.h2[1] = __builtin_amdgcn_cvt_pkrtz(EXP2F(c[2] - MR), EXP2F(c[3] - MR)); \
    ACC = __builtin_amdgcn_mfma_f32_16x16x16f16(av, pw.v4, ACC, 0, 0, 0);      \
  }

__global__ __launch_bounds__(128, 5) void k5pv(
    const uint4* __restrict__ qh, const uint4* __restrict__ ql,
    const uint4* __restrict__ kh, const uint4* __restrict__ kl,
    const _Float16* __restrict__ vfh,
    float* __restrict__ pm, float* __restrict__ pl, float* __restrict__ pa0,
    float* __restrict__ pa1, float* __restrict__ pa2) {
  int tx = threadIdx.x;
  int cb = blockIdx.x & 7;
  int rb = blockIdx.x >> 3;
  int b  = rb >> 5;
  int rc = rb & 31;
  int w = tx >> 6, lane = tx & 63;
  int nl = lane & 15, g = lane >> 4, g1 = g & 1;
  int n0 = rc*128 + w*64;
  size_t pbase = (size_t)b*4096;
  size_t kp0 = (pbase + n0 + nl)*2 + g1;
  bf16x8 bKh0 = *(const bf16x8*)&kh[kp0];
  bf16x8 bKl0 = *(const bf16x8*)&kl[kp0];
  bf16x8 bKh1 = *(const bf16x8*)&kh[kp0 + 32];
  bf16x8 bKl1 = *(const bf16x8*)&kl[kp0 + 32];
  bf16x8 bKh2 = *(const bf16x8*)&kh[kp0 + 64];
  bf16x8 bKl2 = *(const bf16x8*)&kl[kp0 + 64];
  bf16x8 bKh3 = *(const bf16x8*)&kh[kp0 + 96];
  bf16x8 bKl3 = *(const bf16x8*)&kl[kp0 + 96];
  f32x4 zero4 = {0.f, 0.f, 0.f, 0.f};
  size_t cbase = pbase + (size_t)cb*512;
  const uint4* qbase = ((g < 2) ? qh : ql) + (cbase + nl)*2 + g1;
  // ---- pre-pass: chunk-local per-row max (scores >= 0 -> init 0) ----
  float M0 = 0.f, M1 = 0.f, M2 = 0.f, M3 = 0.f;
  {
    const uint4* qp2 = qbase;
    bf16x8 aQn = *(const bf16x8*)qp2;
    #pragma unroll 2
    for (int ct = 0; ct < 32; ++ct) {
      bf16x8 aQ = aQn;
      qp2 += 32;
      if (ct < 31) aQn = *(const bf16x8*)qp2;
      f32x4 c0 = __builtin_amdgcn_mfma_f32_16x16x32_bf16(aQ, bKh0, zero4, 0, 0, 0);
      f32x4 c1 = __builtin_amdgcn_mfma_f32_16x16x32_bf16(aQ, bKh1, zero4, 0, 0, 0);
      f32x4 c2 = __builtin_amdgcn_mfma_f32_16x16x32_bf16(aQ, bKh2, zero4, 0, 0, 0);
      f32x4 c3 = __builtin_amdgcn_mfma_f32_16x16x32_bf16(aQ, bKh3, zero4, 0, 0, 0);
      M0 = fmaxf(fmaxf(fmaxf(M0, c0[0]), fmaxf(c0[1], c0[2])), c0[3]);
      M1 = fmaxf(fmaxf(fmaxf(M1, c1[0]), fmaxf(c1[1], c1[2])), c1[3]);
      M2 = fmaxf(fmaxf(fmaxf(M2, c2[0]), fmaxf(c2[1], c2[2])), c2[3]);
      M3 = fmaxf(fmaxf(fmaxf(M3, c3[0]), fmaxf(c3[1], c3[2])), c3[3]);
    }
    M0 = fmaxf(M0, __shfl_xor(M0, 16)); M0 = fmaxf(M0, __shfl_xor(M0, 32));
    M1 = fmaxf(M1, __shfl_xor(M1, 16)); M1 = fmaxf(M1, __shfl_xor(M1, 32));
    M2 = fmaxf(M2, __shfl_xor(M2, 16)); M2 = fmaxf(M2, __shfl_xor(M2, 32));
    M3 = fmaxf(M3, __shfl_xor(M3, 16)); M3 = fmaxf(M3, __shfl_xor(M3, 32));
  }
  // ---- main pass: fixed-M PV with MFMA-C accumulation + prefetch ----
  f32x4 acc0 = zero4, acc1 = zero4, acc2 = zero4, acc3 = zero4;
  const uint4* qptr = qbase;
  const _Float16* vptr = vfh + (size_t)nl*32768 + cbase + g*4;
  bool vload = (nl < 4);
  f16x4 zeroh = {(_Float16)0.f, (_Float16)0.f, (_Float16)0.f, (_Float16)0.f};
  bf16x8 aQn = *(const bf16x8*)qptr;
  f16x4 avn = zeroh;
  if (vload) avn = *(const f16x4*)vptr;
  #pragma unroll 2
  for (int ct = 0; ct < 32; ++ct) {
    bf16x8 aQ = aQn;
    f16x4 av = avn;
    qptr += 32;
    vptr += 16;
    if (ct < 31) {
      aQn = *(const bf16x8*)qptr;
      if (vload) avn = *(const f16x4*)vptr;
    }
    K5_TILE(bKh0, bKl0, M0, acc0)
    K5_TILE(bKh1, bKl1, M1, acc1)
    K5_TILE(bKh2, bKl2, M2, acc2)
    K5_TILE(bKh3, bKl3, M3, acc3)
  }
  if (lane < 16) {
    size_t base = (size_t)cb*32768 + pbase + n0 + lane;
    pm[base]      = M0; pl[base]      = acc0[3]; pa0[base]      = acc0[0]; pa1[base]      = acc0[1]; pa2[base]      = acc0[2];
    pm[base + 16] = M1; pl[base + 16] = acc1[3]; pa0[base + 16] = acc1[0]; pa1[base + 16] = acc1[1]; pa2[base + 16] = acc1[2];
    pm[base + 32] = M2; pl[base + 32] = acc2[3]; pa0[base + 32] = acc2[0]; pa1[base + 32] = acc2[1]; pa2[base + 32] = acc2[2];
    pm[base + 48] = M3; pl[base + 48] = acc3[3]; pa0[base + 48] = acc3[0]; pa1[base + 48] = acc3[1]; pa2[base + 48] = acc3[2];
  }
}

// ---- k6: max-merge 8 per-chunk partials (log2 domain) + epilogue -----------
__global__ __launch_bounds__(256) void k6_merge(
    const float* __restrict__ pm, const float* __restrict__ pl,
    const float* __restrict__ pa0, const float* __restrict__ pa1,
    const float* __restrict__ pa2, const float* __restrict__ x,
    const float* __restrict__ alpha, float* __restrict__ out) {
  int row = blockIdx.x*256 + threadIdx.x;   // 0..32767
  float m[8];
  #pragma unroll
  for (int cb = 0; cb < 8; ++cb) m[cb] = pm[(size_t)cb*32768 + row];
  float M = fmaxf(fmaxf(fmaxf(m[0], m[1]), fmaxf(m[2], m[3])),
                  fmaxf(fmaxf(m[4], m[5]), fmaxf(m[6], m[7])));
  float L = 0.f, A0 = 0.f, A1 = 0.f, A2 = 0.f;
  #pragma unroll
  for (int cb = 0; cb < 8; ++cb) {
    size_t i = (size_t)cb*32768 + row;
    float ci = EXP2F(m[cb] - M);
    L  = fmaf(pl[i],  ci, L);
    A0 = fmaf(pa0[i], ci, A0);
    A1 = fmaf(pa1[i], ci, A1);
    A2 = fmaf(pa2[i], ci, A2);
  }
  int b = row >> 12, n = row & 4095;
  float inv = 1.f / L, al = alpha[0];
  out[(size_t)(b*3+0)*NN + n] = fmaf(al, A0*inv, x[(size_t)(b*3+0)*NN + n]);
  out[(size_t)(b*3+1)*NN + n] = fmaf(al, A1*inv, x[(size_t)(b*3+1)*NN + n]);
  out[(size_t)(b*3+2)*NN + n] = fmaf(al, A2*inv, x[(size_t)(b*3+2)*NN + n]);
}

extern "C" void kernel_launch(void* const* d_in, const int* in_sizes, int n_in,
                              void* d_out, int out_size, void* d_ws, size_t ws_size,
                              hipStream_t stream) {
  const float* x    = (const float*)d_in[0];
  const float* w1   = (const float*)d_in[1];
  const float* g1   = (const float*)d_in[2];
  const float* b1   = (const float*)d_in[3];
  const float* w2   = (const float*)d_in[4];
  const float* wq   = (const float*)d_in[5];
  const float* g2   = (const float*)d_in[6];
  const float* b2   = (const float*)d_in[7];
  const float* wk   = (const float*)d_in[8];
  const float* g3   = (const float*)d_in[9];
  const float* b3   = (const float*)d_in[10];
  const float* wv   = (const float*)d_in[11];
  const float* g4   = (const float*)d_in[12];
  const float* b4   = (const float*)d_in[13];
  const float* alpha= (const float*)d_in[14];
  float* out = (float*)d_out;
  float* ws  = (float*)d_ws;

  float* qpT = ws + OFF_QPT;
  float* kpT = ws + OFF_KPT;
  float* vpT = ws + OFF_VPT;
  float* wt2 = ws + OFF_WT2;
  float* xp  = ws + OFF_XP;
  float* bst = ws + OFF_BS;
  uint4* qhb = (uint4*)(ws + OFF_QH);
  uint4* qlb = (uint4*)(ws + OFF_QL);
  uint4* khb = (uint4*)(ws + OFF_KH);
  uint4* klb = (uint4*)(ws + OFF_KL);
  _Float16* vfh = (_Float16*)(ws + OFF_VFH);
  float* pls = ws + OFF_PL;
  float* pa0 = ws + OFF_PA0;
  float* pa1 = ws + OFF_PA1;
  float* pa2 = ws + OFF_PA2;
  float* pms = ws + OFF_PM;

  kA_mom_wcomb<<<129, 256, 0, stream>>>(x, xp, w2, wq, wk, wv, wt2);
  kB_qkv<<<256, 128, 0, stream>>>(x, xp, w1, g1, b1, wt2, qpT, kpT, vpT, bst);
  kC_prep<<<128, 256, 0, stream>>>(qpT, kpT, vpT, bst, g2, b2, g3, b3, g4, b4,
                                   qhb, qlb, khb, klb, vfh);
  k5pv<<<2048, 128, 0, stream>>>(qhb, qlb, khb, klb, vfh, pms, pls, pa0, pa1, pa2);
  k6_merge<<<128, 256, 0, stream>>>(pms, pls, pa0, pa1, pa2, x, alpha, out);
}

// Round 21
// 92.470 us; speedup vs baseline: 1.6842x; 1.0103x over previous
//
#include <hip/hip_runtime.h>

#define EPS 1e-5f
constexpr int NN = 4096;
constexpr float INV_CNT = 1.0f / (8.0f * 4096.0f);
constexpr float LOG2E = 1.44269504f;

typedef __attribute__((ext_vector_type(8))) short bf16x8;
typedef __attribute__((ext_vector_type(4))) float f32x4;
typedef __attribute__((ext_vector_type(4))) _Float16 f16x4;
typedef __fp16 fp16x2 __attribute__((ext_vector_type(2)));

#if __has_builtin(__builtin_amdgcn_exp2f)
#define EXP2F(x) __builtin_amdgcn_exp2f(x)
#else
#define EXP2F(x) exp2f(x)
#endif

// workspace layout (float offsets)
constexpr size_t OFF_QPT = 0;        // 524288
constexpr size_t OFF_KPT = 524288;   // 524288
constexpr size_t OFF_VPT = 1048576;  // 131072
constexpr size_t OFF_WT2 = 1179648;  // 2304
constexpr size_t OFF_XP  = 1181952;  // 1152
constexpr size_t OFF_BS  = 1183104;  // 17920
constexpr size_t OFF_QH  = 1201024;  // 262144
constexpr size_t OFF_QL  = 1463168;  // 262144
constexpr size_t OFF_KH  = 1725312;  // 262144
constexpr size_t OFF_KL  = 1987456;  // 262144
constexpr size_t OFF_VFH = 2249600;  // 262144 (16 rows x 32768 fp16; rows 0-3 live)
constexpr size_t OFF_PL  = 2511744;  // 8*32768 = 262144
constexpr size_t OFF_PA0 = 2773888;  // 262144
constexpr size_t OFF_PA1 = 3036032;  // 262144
constexpr size_t OFF_PA2 = 3298176;  // 262144
constexpr size_t OFF_PM  = 3560320;  // 8*32768 = 262144; end 3822464 = 15.3 MB

// ---- kA: blocks 0-127: x moments; block 128: combined weights --------------
__global__ __launch_bounds__(256) void kA_mom_wcomb(
    const float* __restrict__ x, float* __restrict__ xpart,
    const float* __restrict__ w2, const float* __restrict__ wq,
    const float* __restrict__ wk, const float* __restrict__ wv,
    float* __restrict__ wt2) {
  __shared__ float w2s[8192];
  __shared__ float wr[4480];
  __shared__ float sred[36];
  int tx = threadIdx.x;
  if (blockIdx.x < 128) {
    int idx = blockIdx.x * 256 + tx;
    int b = idx >> 12, n = idx & 4095;
    float x0 = x[(size_t)(b*3+0)*NN + n];
    float x1 = x[(size_t)(b*3+1)*NN + n];
    float x2 = x[(size_t)(b*3+2)*NN + n];
    float m[9] = {x0, x1, x2, x0*x0, x0*x1, x0*x2, x1*x1, x1*x2, x2*x2};
    #pragma unroll
    for (int off = 32; off; off >>= 1) {
      #pragma unroll
      for (int j = 0; j < 9; ++j) m[j] += __shfl_xor(m[j], off);
    }
    int w = tx >> 6;
    if ((tx & 63) == 0) {
      #pragma unroll
      for (int j = 0; j < 9; ++j) sred[w*9+j] = m[j];
    }
    __syncthreads();
    if (tx < 9) xpart[tx*128 + blockIdx.x] = sred[tx] + sred[9+tx] + sred[18+tx] + sred[27+tx];
  } else {
    for (int i = tx; i < 8192; i += 256) w2s[i] = w2[i];
    for (int i = tx; i < 2048; i += 256) { wr[i] = wq[i]; wr[2048+i] = wk[i]; }
    for (int i = tx; i < 384; i += 256) wr[4096+i] = wv[i];
    __syncthreads();
    for (int e = tx; e < 2240; e += 256) {
      int j = e >> 6, c = e & 63;
      float s = 0.f;
      #pragma unroll 4
      for (int o = 0; o < 128; ++o) s = fmaf(wr[j*128+o], w2s[o*64+c], s);
      wt2[c*36 + j] = s;
    }
  }
}

// ---- kB: (f1 fused) per point -> qa/ka/va + block-partial stats ------------
__global__ __launch_bounds__(128) void kB_qkv(
    const float* __restrict__ x, const float* __restrict__ xpart,
    const float* __restrict__ w1, const float* __restrict__ g1,
    const float* __restrict__ b1, const float* __restrict__ wt2,
    float* __restrict__ qpT, float* __restrict__ kpT, float* __restrict__ vpT,
    float* __restrict__ bs) {
  __shared__ float4 w1s[64];
  __shared__ float4 wt2s[576];
  __shared__ float sred[140];
  __shared__ float mom[9];
  int tx = threadIdx.x;
  for (int i = tx; i < 576; i += 128) wt2s[i] = ((const float4*)wt2)[i];
  if (tx < 9) {
    float acc = 0.f;
    #pragma unroll 8
    for (int i = 0; i < 128; ++i) acc += xpart[tx*128 + i];
    mom[tx] = acc * INV_CNT;
  }
  __syncthreads();
  if (tx < 64) {
    int c = tx;
    float a = w1[c*3], b_ = w1[c*3+1], d = w1[c*3+2];
    float mean = a*mom[0] + b_*mom[1] + d*mom[2];
    float e2 = a*a*mom[3] + b_*b_*mom[6] + d*d*mom[8]
             + 2.f*(a*b_*mom[4] + a*d*mom[5] + b_*d*mom[7]);
    float sc = g1[c] * rsqrtf(e2 - mean*mean + EPS);
    w1s[c] = make_float4(a*sc, b_*sc, d*sc, fmaf(-mean, sc, b1[c]));
  }
  __syncthreads();
  int idx = blockIdx.x*128 + tx;
  int b = idx >> 12, n = idx & 4095;
  float x0 = x[(size_t)(b*3+0)*NN + n];
  float x1 = x[(size_t)(b*3+1)*NN + n];
  float x2 = x[(size_t)(b*3+2)*NN + n];
  float qa[16] = {}, ka[16] = {};
  float va0 = 0.f, va1 = 0.f, va2 = 0.f;
  #pragma unroll 4
  for (int c = 0; c < 64; ++c) {
    float4 w = w1s[c];
    float h = fmaf(w.x, x0, fmaf(w.y, x1, fmaf(w.z, x2, w.w)));
    h = h > 0.f ? h : 0.2f*h;
    #pragma unroll
    for (int j = 0; j < 4; ++j) {
      float4 A = wt2s[c*9 + j];
      qa[4*j+0] = fmaf(A.x, h, qa[4*j+0]);
      qa[4*j+1] = fmaf(A.y, h, qa[4*j+1]);
      qa[4*j+2] = fmaf(A.z, h, qa[4*j+2]);
      qa[4*j+3] = fmaf(A.w, h, qa[4*j+3]);
      float4 B = wt2s[c*9 + 4 + j];
      ka[4*j+0] = fmaf(B.x, h, ka[4*j+0]);
      ka[4*j+1] = fmaf(B.y, h, ka[4*j+1]);
      ka[4*j+2] = fmaf(B.z, h, ka[4*j+2]);
      ka[4*j+3] = fmaf(B.w, h, ka[4*j+3]);
    }
    float4 V = wt2s[c*9 + 8];
    va0 = fmaf(V.x, h, va0); va1 = fmaf(V.y, h, va1); va2 = fmaf(V.z, h, va2);
  }
  float4* qo = (float4*)(qpT + (size_t)idx*16);
  float4* ko = (float4*)(kpT + (size_t)idx*16);
  #pragma unroll
  for (int j = 0; j < 4; ++j) {
    qo[j] = make_float4(qa[4*j], qa[4*j+1], qa[4*j+2], qa[4*j+3]);
    ko[j] = make_float4(ka[4*j], ka[4*j+1], ka[4*j+2], ka[4*j+3]);
  }
  ((float4*)vpT)[idx] = make_float4(va0, va1, va2, 0.f);
  int w = tx >> 6;
  bool lead = ((tx & 63) == 0);
  #pragma unroll
  for (int d = 0; d < 16; ++d) {
    float s = qa[d], q = qa[d]*qa[d];
    #pragma unroll
    for (int off = 32; off; off >>= 1) { s += __shfl_xor(s, off); q += __shfl_xor(q, off); }
    if (lead) { sred[w*70 + d] = s; sred[w*70 + 16 + d] = q; }
    s = ka[d]; q = ka[d]*ka[d];
    #pragma unroll
    for (int off = 32; off; off >>= 1) { s += __shfl_xor(s, off); q += __shfl_xor(q, off); }
    if (lead) { sred[w*70 + 32 + d] = s; sred[w*70 + 48 + d] = q; }
  }
  float vv[3] = {va0, va1, va2};
  #pragma unroll
  for (int d = 0; d < 3; ++d) {
    float s = vv[d], q = vv[d]*vv[d];
    #pragma unroll
    for (int off = 32; off; off >>= 1) { s += __shfl_xor(s, off); q += __shfl_xor(q, off); }
    if (lead) { sred[w*70 + 64 + d] = s; sred[w*70 + 67 + d] = q; }
  }
  __syncthreads();
  if (tx < 70)
    bs[tx*256 + blockIdx.x] = sred[tx] + sred[70+tx];
}

// ---- kC: (f2 fused) BN+ReLU, q scaled by log2e, hi/lo split, v->fp16 -------
__global__ __launch_bounds__(256) void kC_prep(
    const float* __restrict__ qpT, const float* __restrict__ kpT,
    const float* __restrict__ vpT, const float* __restrict__ bs,
    const float* __restrict__ g2, const float* __restrict__ b2,
    const float* __restrict__ g3, const float* __restrict__ b3,
    const float* __restrict__ g4, const float* __restrict__ b4,
    uint4* __restrict__ qh, uint4* __restrict__ ql,
    uint4* __restrict__ kh, uint4* __restrict__ kl,
    _Float16* __restrict__ vfh) {
  __shared__ float tot[70];
  __shared__ float spr[70];
  int tx = threadIdx.x;
  if (tx < 70) {
    float acc = 0.f;
    #pragma unroll 8
    for (int i = 0; i < 256; ++i) acc += bs[tx*256 + i];
    tot[tx] = acc * INV_CNT;
  }
  __syncthreads();
  if (tx < 16) {
    float mean = tot[tx], var = tot[16+tx] - mean*mean;
    float sc = g2[tx]*rsqrtf(var + EPS);
    spr[tx] = sc * LOG2E;
    spr[16+tx] = fmaf(-mean, sc, b2[tx]) * LOG2E;
  } else if (tx < 32) {
    int d = tx-16;
    float mean = tot[32+d], var = tot[48+d] - mean*mean;
    float sc = g3[d]*rsqrtf(var + EPS);
    spr[32+d] = sc; spr[48+d] = fmaf(-mean, sc, b3[d]);
  } else if (tx < 35) {
    int d = tx-32;
    float mean = tot[64+d], var = tot[67+d] - mean*mean;
    float sc = g4[d]*rsqrtf(var + EPS);
    spr[64+d] = sc; spr[67+d] = fmaf(-mean, sc, b4[d]);
  }
  __syncthreads();
  int p = blockIdx.x*256 + tx;
  float qv[16], kv[16];
  const float4* q4 = (const float4*)(qpT + (size_t)p*16);
  const float4* k4p = (const float4*)(kpT + (size_t)p*16);
  #pragma unroll
  for (int j = 0; j < 4; ++j) {
    float4 tq = q4[j], tk = k4p[j];
    qv[4*j] = tq.x; qv[4*j+1] = tq.y; qv[4*j+2] = tq.z; qv[4*j+3] = tq.w;
    kv[4*j] = tk.x; kv[4*j+1] = tk.y; kv[4*j+2] = tk.z; kv[4*j+3] = tk.w;
  }
  #pragma unroll
  for (int d = 0; d < 16; ++d) {
    qv[d] = fmaxf(fmaf(qv[d], spr[d],    spr[16+d]), 0.f);
    kv[d] = fmaxf(fmaf(kv[d], spr[32+d], spr[48+d]), 0.f);
  }
  unsigned qhw[8], qlw[8], khw[8], klw[8];
  #pragma unroll
  for (int j = 0; j < 8; ++j) {
    unsigned u0 = __float_as_uint(qv[2*j]),   u1 = __float_as_uint(qv[2*j+1]);
    unsigned h0 = u0 & 0xFFFF0000u, h1 = u1 & 0xFFFF0000u;
    float l0 = qv[2*j] - __uint_as_float(h0);
    float l1 = qv[2*j+1] - __uint_as_float(h1);
    qhw[j] = (h0 >> 16) | h1;
    qlw[j] = (__float_as_uint(l0) >> 16) | (__float_as_uint(l1) & 0xFFFF0000u);
    u0 = __float_as_uint(kv[2*j]); u1 = __float_as_uint(kv[2*j+1]);
    h0 = u0 & 0xFFFF0000u; h1 = u1 & 0xFFFF0000u;
    l0 = kv[2*j] - __uint_as_float(h0);
    l1 = kv[2*j+1] - __uint_as_float(h1);
    khw[j] = (h0 >> 16) | h1;
    klw[j] = (__float_as_uint(l0) >> 16) | (__float_as_uint(l1) & 0xFFFF0000u);
  }
  qh[(size_t)p*2+0] = make_uint4(qhw[0], qhw[1], qhw[2], qhw[3]);
  qh[(size_t)p*2+1] = make_uint4(qhw[4], qhw[5], qhw[6], qhw[7]);
  ql[(size_t)p*2+0] = make_uint4(qlw[0], qlw[1], qlw[2], qlw[3]);
  ql[(size_t)p*2+1] = make_uint4(qlw[4], qlw[5], qlw[6], qlw[7]);
  kh[(size_t)p*2+0] = make_uint4(khw[0], khw[1], khw[2], khw[3]);
  kh[(size_t)p*2+1] = make_uint4(khw[4], khw[5], khw[6], khw[7]);
  kl[(size_t)p*2+0] = make_uint4(klw[0], klw[1], klw[2], klw[3]);
  kl[(size_t)p*2+1] = make_uint4(klw[4], klw[5], klw[6], klw[7]);
  float4 vv = ((const float4*)vpT)[p];
  vfh[0*32768 + p] = (_Float16)fmaxf(fmaf(vv.x, spr[64], spr[67]), 0.f);
  vfh[1*32768 + p] = (_Float16)fmaxf(fmaf(vv.y, spr[65], spr[68]), 0.f);
  vfh[2*32768 + p] = (_Float16)fmaxf(fmaf(vv.z, spr[66], spr[69]), 0.f);
  vfh[3*32768 + p] = (_Float16)1.0f;
}

// ---- k5pv: fused chunk-local max pre-pass + fixed-M PV loop ----------------
// Pre-pass M_chunk[r] = max over this 512-col chunk of (qh+ql)·kh — a lower
// bound of the full score with gap <= (qh+ql)·kl ~ 0.78 log2 => pw <= 1.72,
// fp16-safe; softmax exact after k6's max-merge (R10-verified pattern).
// blk: cb = blk&7 (512-col chunk), rb = blk>>3: b = rb>>5, rc = rb&31.
#define K5_TILE(BKH, BKL, MR, ACC)                                             \
  {                                                                            \
    f32x4 c = __builtin_amdgcn_mfma_f32_16x16x32_bf16(aQ, BKH, zero4, 0, 0, 0);\
    c = __builtin_amdgcn_mfma_f32_16x16x32_bf16(aQ, BKL, c, 0, 0, 0);          \
    union { fp16x2 h2[2]; f16x4 v4; } pw;                                      \
    pw.h2[0] = __builtin_amdgcn_cvt_pkrtz(EXP2F(c[0] - MR), EXP2F(c[1] - MR)); \
    pw.h2[1] = __builtin_amdgcn_cvt_pkrtz(EXP2F(c[2] - MR), EXP2F(c[3] - MR)); \
    ACC = __builtin_amdgcn_mfma_f32_16x16x16f16(av, pw.v4, ACC, 0, 0, 0);      \
  }

__global__ __launch_bounds__(128, 5) void k5pv(
    const uint4* __restrict__ qh, const uint4* __restrict__ ql,
    const uint4* __restrict__ kh, const uint4* __restrict__ kl,
    const _Float16* __restrict__ vfh,
    float* __restrict__ pm, float* __restrict__ pl, float* __restrict__ pa0,
    float* __restrict__ pa1, float* __restrict__ pa2) {
  int tx = threadIdx.x;
  int cb = blockIdx.x & 7;
  int rb = blockIdx.x >> 3;
  int b  = rb >> 5;
  int rc = rb & 31;
  int w = tx >> 6, lane = tx & 63;
  int nl = lane & 15, g = lane >> 4, g1 = g & 1;
  int n0 = rc*128 + w*64;
  size_t pbase = (size_t)b*4096;
  size_t kp0 = (pbase + n0 + nl)*2 + g1;
  bf16x8 bKh0 = *(const bf16x8*)&kh[kp0];
  bf16x8 bKl0 = *(const bf16x8*)&kl[kp0];
  bf16x8 bKh1 = *(const bf16x8*)&kh[kp0 + 32];
  bf16x8 bKl1 = *(const bf16x8*)&kl[kp0 + 32];
  bf16x8 bKh2 = *(const bf16x8*)&kh[kp0 + 64];
  bf16x8 bKl2 = *(const bf16x8*)&kl[kp0 + 64];
  bf16x8 bKh3 = *(const bf16x8*)&kh[kp0 + 96];
  bf16x8 bKl3 = *(const bf16x8*)&kl[kp0 + 96];
  f32x4 zero4 = {0.f, 0.f, 0.f, 0.f};
  size_t cbase = pbase + (size_t)cb*512;
  const uint4* qbase = ((g < 2) ? qh : ql) + (cbase + nl)*2 + g1;
  // ---- pre-pass: chunk-local per-row max (scores >= 0 -> init 0) ----
  float M0 = 0.f, M1 = 0.f, M2 = 0.f, M3 = 0.f;
  {
    const uint4* qp2 = qbase;
    bf16x8 aQn = *(const bf16x8*)qp2;
    #pragma unroll 2
    for (int ct = 0; ct < 32; ++ct) {
      bf16x8 aQ = aQn;
      qp2 += 32;
      if (ct < 31) aQn = *(const bf16x8*)qp2;
      f32x4 c0 = __builtin_amdgcn_mfma_f32_16x16x32_bf16(aQ, bKh0, zero4, 0, 0, 0);
      f32x4 c1 = __builtin_amdgcn_mfma_f32_16x16x32_bf16(aQ, bKh1, zero4, 0, 0, 0);
      f32x4 c2 = __builtin_amdgcn_mfma_f32_16x16x32_bf16(aQ, bKh2, zero4, 0, 0, 0);
      f32x4 c3 = __builtin_amdgcn_mfma_f32_16x16x32_bf16(aQ, bKh3, zero4, 0, 0, 0);
      M0 = fmaxf(fmaxf(fmaxf(M0, c0[0]), fmaxf(c0[1], c0[2])), c0[3]);
      M1 = fmaxf(fmaxf(fmaxf(M1, c1[0]), fmaxf(c1[1], c1[2])), c1[3]);
      M2 = fmaxf(fmaxf(fmaxf(M2, c2[0]), fmaxf(c2[1], c2[2])), c2[3]);
      M3 = fmaxf(fmaxf(fmaxf(M3, c3[0]), fmaxf(c3[1], c3[2])), c3[3]);
    }
    M0 = fmaxf(M0, __shfl_xor(M0, 16)); M0 = fmaxf(M0, __shfl_xor(M0, 32));
    M1 = fmaxf(M1, __shfl_xor(M1, 16)); M1 = fmaxf(M1, __shfl_xor(M1, 32));
    M2 = fmaxf(M2, __shfl_xor(M2, 16)); M2 = fmaxf(M2, __shfl_xor(M2, 32));
    M3 = fmaxf(M3, __shfl_xor(M3, 16)); M3 = fmaxf(M3, __shfl_xor(M3, 32));
  }
  // ---- main pass: fixed-M PV with MFMA-C accumulation + prefetch ----
  f32x4 acc0 = zero4, acc1 = zero4, acc2 = zero4, acc3 = zero4;
  const uint4* qptr = qbase;
  const _Float16* vptr = vfh + (size_t)nl*32768 + cbase + g*4;
  bool vload = (nl < 4);
  f16x4 zeroh = {(_Float16)0.f, (_Float16)0.f, (_Float16)0.f, (_Float16)0.f};
  bf16x8 aQn = *(const bf16x8*)qptr;
  f16x4 avn = zeroh;
  if (vload) avn = *(const f16x4*)vptr;
  #pragma unroll 2
  for (int ct = 0; ct < 32; ++ct) {
    bf16x8 aQ = aQn;
    f16x4 av = avn;
    qptr += 32;
    vptr += 16;
    if (ct < 31) {
      aQn = *(const bf16x8*)qptr;
      if (vload) avn = *(const f16x4*)vptr;
    }
    K5_TILE(bKh0, bKl0, M0, acc0)
    K5_TILE(bKh1, bKl1, M1, acc1)
    K5_TILE(bKh2, bKl2, M2, acc2)
    K5_TILE(bKh3, bKl3, M3, acc3)
  }
  if (lane < 16) {
    size_t base = (size_t)cb*32768 + pbase + n0 + lane;
    pm[base]      = M0; pl[base]      = acc0[3]; pa0[base]      = acc0[0]; pa1[base]      = acc0[1]; pa2[base]      = acc0[2];
    pm[base + 16] = M1; pl[base + 16] = acc1[3]; pa0[base + 16] = acc1[0]; pa1[base + 16] = acc1[1]; pa2[base + 16] = acc1[2];
    pm[base + 32] = M2; pl[base + 32] = acc2[3]; pa0[base + 32] = acc2[0]; pa1[base + 32] = acc2[1]; pa2[base + 32] = acc2[2];
    pm[base + 48] = M3; pl[base + 48] = acc3[3]; pa0[base + 48] = acc3[0]; pa1[base + 48] = acc3[1]; pa2[base + 48] = acc3[2];
  }
}

// ---- k6: max-merge 8 per-chunk partials (log2 domain) + epilogue -----------
__global__ __launch_bounds__(256) void k6_merge(
    const float* __restrict__ pm, const float* __restrict__ pl,
    const float* __restrict__ pa0, const float* __restrict__ pa1,
    const float* __restrict__ pa2, const float* __restrict__ x,
    const float* __restrict__ alpha, float* __restrict__ out) {
  int row = blockIdx.x*256 + threadIdx.x;   // 0..32767
  float m[8];
  #pragma unroll
  for (int cb = 0; cb < 8; ++cb) m[cb] = pm[(size_t)cb*32768 + row];
  float M = fmaxf(fmaxf(fmaxf(m[0], m[1]), fmaxf(m[2], m[3])),
                  fmaxf(fmaxf(m[4], m[5]), fmaxf(m[6], m[7])));
  float L = 0.f, A0 = 0.f, A1 = 0.f, A2 = 0.f;
  #pragma unroll
  for (int cb = 0; cb < 8; ++cb) {
    size_t i = (size_t)cb*32768 + row;
    float ci = EXP2F(m[cb] - M);
    L  = fmaf(pl[i],  ci, L);
    A0 = fmaf(pa0[i], ci, A0);
    A1 = fmaf(pa1[i], ci, A1);
    A2 = fmaf(pa2[i], ci, A2);
  }
  int b = row >> 12, n = row & 4095;
  float inv = 1.f / L, al = alpha[0];
  out[(size_t)(b*3+0)*NN + n] = fmaf(al, A0*inv, x[(size_t)(b*3+0)*NN + n]);
  out[(size_t)(b*3+1)*NN + n] = fmaf(al, A1*inv, x[(size_t)(b*3+1)*NN + n]);
  out[(size_t)(b*3+2)*NN + n] = fmaf(al, A2*inv, x[(size_t)(b*3+2)*NN + n]);
}

extern "C" void kernel_launch(void* const* d_in, const int* in_sizes, int n_in,
                              void* d_out, int out_size, void* d_ws, size_t ws_size,
                              hipStream_t stream) {
  const float* x    = (const float*)d_in[0];
  const float* w1   = (const float*)d_in[1];
  const float* g1   = (const float*)d_in[2];
  const float* b1   = (const float*)d_in[3];
  const float* w2   = (const float*)d_in[4];
  const float* wq   = (const float*)d_in[5];
  const float* g2   = (const float*)d_in[6];
  const float* b2   = (const float*)d_in[7];
  const float* wk   = (const float*)d_in[8];
  const float* g3   = (const float*)d_in[9];
  const float* b3   = (const float*)d_in[10];
  const float* wv   = (const float*)d_in[11];
  const float* g4   = (const float*)d_in[12];
  const float* b4   = (const float*)d_in[13];
  const float* alpha= (const float*)d_in[14];
  float* out = (float*)d_out;
  float* ws  = (float*)d_ws;

  float* qpT = ws + OFF_QPT;
  float* kpT = ws + OFF_KPT;
  float* vpT = ws + OFF_VPT;
  float* wt2 = ws + OFF_WT2;
  float* xp  = ws + OFF_XP;
  float* bst = ws + OFF_BS;
  uint4* qhb = (uint4*)(ws + OFF_QH);
  uint4* qlb = (uint4*)(ws + OFF_QL);
  uint4* khb = (uint4*)(ws + OFF_KH);
  uint4* klb = (uint4*)(ws + OFF_KL);
  _Float16* vfh = (_Float16*)(ws + OFF_VFH);
  float* pls = ws + OFF_PL;
  float* pa0 = ws + OFF_PA0;
  float* pa1 = ws + OFF_PA1;
  float* pa2 = ws + OFF_PA2;
  float* pms = ws + OFF_PM;

  kA_mom_wcomb<<<129, 256, 0, stream>>>(x, xp, w2, wq, wk, wv, wt2);
  kB_qkv<<<256, 128, 0, stream>>>(x, xp, w1, g1, b1, wt2, qpT, kpT, vpT, bst);
  kC_prep<<<128, 256, 0, stream>>>(qpT, kpT, vpT, bst, g2, b2, g3, b3, g4, b4,
                                   qhb, qlb, khb, klb, vfh);
  k5pv<<<2048, 128, 0, stream>>>(qhb, qlb, khb, klb, vfh, pms, pls, pa0, pa1, pa2);
  k6_merge<<<128, 256, 0, stream>>>(pms, pls, pa0, pa1, pa2, x, alpha, out);
}